// Round 11
// baseline (455.528 us; speedup 1.0000x reference)
//
#include <hip/hip_runtime.h>
#include <stdint.h>

#define NN 50000
#define NE 800000
#define NR (NN*8)            // (node, relation) segments
#define SCAN_BS 512
#define NB2 782              // ceil(NR/512)
#define INV_N (1.0f/50000.0f)
#define BN_EPS 1e-5f

typedef unsigned short ushort_t;
typedef unsigned char uchar_t;
typedef short bf16x8 __attribute__((ext_vector_type(8)));   // 8 bf16 (4 VGPRs)
typedef float f32x4 __attribute__((ext_vector_type(4)));
typedef float f32x2 __attribute__((ext_vector_type(2)));

__device__ __forceinline__ ushort_t f2bf(float f){
    unsigned int u = __float_as_uint(f);
    u += 0x7FFFu + ((u >> 16) & 1u);      // RNE
    return (ushort_t)(u >> 16);
}
__device__ __forceinline__ float bf2f(ushort_t h){ return __uint_as_float(((unsigned int)h) << 16); }
__device__ __forceinline__ float bflo(unsigned int u){ return __uint_as_float(u << 16); }
__device__ __forceinline__ float bfhi(unsigned int u){ return __uint_as_float(u & 0xFFFF0000u); }

// fp8 e4m3 (OCP) helpers via HW converters
__device__ __forceinline__ unsigned int f4_to_fp8(float a, float b, float c, float d){
    int v = __builtin_amdgcn_cvt_pk_fp8_f32(a, b, 0, false);
    v = __builtin_amdgcn_cvt_pk_fp8_f32(c, d, v, true);
    return (unsigned int)v;
}
__device__ __forceinline__ void fp8_to_f4(unsigned int u, float& a, float& b, float& c, float& d){
    f32x2 lo = __builtin_amdgcn_cvt_pk_f32_fp8(u, false);
    f32x2 hi = __builtin_amdgcn_cvt_pk_f32_fp8(u, true);
    a = lo.x; b = lo.y; c = hi.x; d = hi.y;
}

// ---------------------------------------------------------------------------
// CSR build over (dst, relation) segments
// ---------------------------------------------------------------------------
__global__ void k_deg(const int* __restrict__ ei, const int* __restrict__ et, int* __restrict__ deg){
    int e = blockIdx.x*256 + threadIdx.x;
    if (e < NE) atomicAdd(&deg[ei[NE + e]*8 + et[e]], 1);
}

__global__ void k_scan1(const int* __restrict__ deg, int* __restrict__ tmp, int* __restrict__ bsum){
    __shared__ int s[SCAN_BS];
    int t = threadIdx.x;
    int i = blockIdx.x*SCAN_BS + t;
    s[t] = (i < NR) ? deg[i] : 0;
    __syncthreads();
    for (int off = 1; off < SCAN_BS; off <<= 1){
        int add = (t >= off) ? s[t-off] : 0;
        __syncthreads();
        s[t] += add;
        __syncthreads();
    }
    if (i < NR) tmp[i] = s[t];
    if (t == SCAN_BS-1) bsum[blockIdx.x] = s[t];
}

__global__ void k_scan2(int* __restrict__ bsum){
    __shared__ int s[NB2];
    int t = threadIdx.x;
    if (t < NB2) s[t] = bsum[t];
    __syncthreads();
    if (t == 0){
        int acc = 0;
        for (int i = 0; i < NB2; ++i){ acc += s[i]; s[i] = acc; }
    }
    __syncthreads();
    if (t < NB2) bsum[t] = s[t];
}

__global__ void k_scan3(const int* __restrict__ tmp, const int* __restrict__ bsum, int* __restrict__ rs){
    int i = blockIdx.x*256 + threadIdx.x;
    if (i < NR){
        int b = i >> 9;
        int off = (b > 0) ? bsum[b-1] : 0;
        rs[i+1] = tmp[i] + off;
        if (i == 0) rs[0] = 0;
    }
}

__global__ void k_fill(const int* __restrict__ ei, const int* __restrict__ et,
                       const int* __restrict__ rs, int* __restrict__ cursor, int* __restrict__ csr){
    int e = blockIdx.x*256 + threadIdx.x;
    if (e < NE){
        int seg = ei[NE + e]*8 + et[e];
        int pos = atomicAdd(&cursor[seg], 1);
        csr[rs[seg] + pos] = ei[e];
    }
}

// ---------------------------------------------------------------------------
// Prep: cast nf->bf16 (xb) + fp8 (xb8), bf16 weight tables, concat biases
// ---------------------------------------------------------------------------
__global__ void k_prep(const float* __restrict__ nf,
                       const float* __restrict__ rgcn_w, const float* __restrict__ root,
                       const float* __restrict__ wq, const float* __restrict__ wk,
                       const float* __restrict__ wv, const float* __restrict__ wsk,
                       const float* __restrict__ bq, const float* __restrict__ bk,
                       const float* __restrict__ bv, const float* __restrict__ bsk,
                       const float* __restrict__ wl, const float* __restrict__ wr,
                       ushort_t* __restrict__ xb, uchar_t* __restrict__ xb8,
                       ushort_t* __restrict__ Wcat,
                       ushort_t* __restrict__ Wt2, float* __restrict__ bcat,
                       ushort_t* __restrict__ Wsage){
    int i = blockIdx.x*256 + threadIdx.x;
    const int NXB = NN*16;
    if (i < NXB){
        float4 v = ((const float4*)nf)[i];
        ushort4 h;
        h.x = f2bf(v.x); h.y = f2bf(v.y); h.z = f2bf(v.z); h.w = f2bf(v.w);
        ((ushort4*)xb)[i] = h;
        ((unsigned int*)xb8)[i] = f4_to_fp8(v.x, v.y, v.z, v.w);
        return;
    }
    int j = i - NXB;
    if (j < 64*576){
        int h = j / 576, k = j - h*576;
        float v = (k < 512) ? rgcn_w[(size_t)k*64 + h] : root[(size_t)(k-512)*64 + h];
        Wcat[j] = f2bf(v);
    } else if (j < 64*576 + 512*64){
        int jj = j - 64*576;
        int c = jj >> 6, k = jj & 63;
        int mt = c >> 7, cc = c & 127;
        const float* W = (mt==0)?wq:(mt==1)?wk:(mt==2)?wv:wsk;
        Wt2[jj] = f2bf(W[(size_t)k*128 + cc]);
    } else if (j < 64*576 + 512*64 + 512){
        int c = j - (64*576 + 512*64);
        int mt = c >> 7, cc = c & 127;
        const float* B = (mt==0)?bq:(mt==1)?bk:(mt==2)?bv:bsk;
        bcat[c] = B[cc];
    } else if (j < 64*576 + 512*64 + 512 + 32*256){
        int jj = j - (64*576 + 512*64 + 512);
        int c = jj >> 8, k = jj & 255;
        float v = (k < 128) ? wr[(size_t)k*32 + c] : wl[(size_t)(k-128)*32 + c];
        Wsage[jj] = f2bf(v);
    }
}

// ---------------------------------------------------------------------------
// FUSED RGCN. Phase 1: quad owns relations {quad,quad+4} (4 gathers in
// flight/lane); node j+1's rs row + csr chunk issued BEFORE node j's gather
// loop (prefetch addr depends only on current rb). Phase 2: 16x64 MFMA, K=576.
// ---------------------------------------------------------------------------
__global__ __launch_bounds__(256) void rgcn_fused(const ushort_t* __restrict__ xb,
                                                  const uchar_t* __restrict__ xb8,
                                                  const int* __restrict__ rs,
                                                  const int* __restrict__ csr,
                                                  const ushort_t* __restrict__ Wcat,
                                                  const float* __restrict__ bias,
                                                  float* __restrict__ h1pre){
    __shared__ ushort_t Ml[16*520];
    int w = threadIdx.x >> 6, lane = threadIdx.x & 63;
    int quad = lane >> 4, l4 = lane & 15;
    int row0 = blockIdx.x * 16;                 // 3125*16 == 50000 exactly
    int n0 = row0 + w*4;
    int rsel = (lane < 9 ? lane : 8);
    int rb = rs[n0*8 + rsel];
    int eb0 = __shfl(rb, 0);
    int dg0 = __shfl(rb, 8) - eb0;
    int idx = (lane < dg0) ? csr[eb0 + lane] : 0;
    for (int j = 0; j < 4; ++j){
        int lrow = (w*4 + j)*520;
        int ebase = __shfl(rb, 0);
        int enext = __shfl(rb, 8);
        int rb_next = 0, idxn = 0;
        if (j < 3){
            rb_next = rs[(n0 + j + 1)*8 + rsel];
            idxn = csr[min(enext + lane, NE - 1)];   // addr independent of rb_next
        }
        int e0a = __shfl(rb, quad),     e1a = __shfl(rb, quad + 1);
        int e0b = __shfl(rb, quad + 4), e1b = __shfl(rb, quad + 5);
        int oa = e0a - ebase, la = e1a - e0a;
        int ob = e0b - ebase, lb = e1b - e0b;
        int ml = max(la, lb);
        ml = max(ml, __shfl_xor(ml, 16));
        ml = max(ml, __shfl_xor(ml, 32));
        float aa0=0.f, aa1=0.f, aa2=0.f, aa3=0.f;
        float ab0=0.f, ab1=0.f, ab2=0.f, ab3=0.f;
        for (int i = 0; i < ml; i += 2){
            int jA0 = oa + i, jA1 = oa + i + 1;
            int jB0 = ob + i, jB1 = ob + i + 1;
            bool vA0 = i < la, vA1 = i + 1 < la;
            bool vB0 = i < lb, vB1 = i + 1 < lb;
            int sA0 = __shfl(idx, jA0 & 63);
            int sA1 = __shfl(idx, jA1 & 63);
            int sB0 = __shfl(idx, jB0 & 63);
            int sB1 = __shfl(idx, jB1 & 63);
            if (jA0 >= 64 && vA0) sA0 = csr[ebase + jA0];   // rare (deg>64)
            if (jA1 >= 64 && vA1) sA1 = csr[ebase + jA1];
            if (jB0 >= 64 && vB0) sB0 = csr[ebase + jB0];
            if (jB1 >= 64 && vB1) sB1 = csr[ebase + jB1];
            sA0 = vA0 ? sA0 : 0; sA1 = vA1 ? sA1 : 0;
            sB0 = vB0 ? sB0 : 0; sB1 = vB1 ? sB1 : 0;
            unsigned int uA0 = *(const unsigned int*)(xb8 + (size_t)sA0*64 + l4*4);
            unsigned int uA1 = *(const unsigned int*)(xb8 + (size_t)sA1*64 + l4*4);
            unsigned int uB0 = *(const unsigned int*)(xb8 + (size_t)sB0*64 + l4*4);
            unsigned int uB1 = *(const unsigned int*)(xb8 + (size_t)sB1*64 + l4*4);
            float f0,f1,f2,f3;
            fp8_to_f4(uA0,f0,f1,f2,f3); if (vA0){ aa0+=f0; aa1+=f1; aa2+=f2; aa3+=f3; }
            fp8_to_f4(uA1,f0,f1,f2,f3); if (vA1){ aa0+=f0; aa1+=f1; aa2+=f2; aa3+=f3; }
            fp8_to_f4(uB0,f0,f1,f2,f3); if (vB0){ ab0+=f0; ab1+=f1; ab2+=f2; ab3+=f3; }
            fp8_to_f4(uB1,f0,f1,f2,f3); if (vB1){ ab0+=f0; ab1+=f1; ab2+=f2; ab3+=f3; }
        }
        float inva = 1.f / fmaxf((float)la, 1.f);
        float invb = 1.f / fmaxf((float)lb, 1.f);
        ushort4 oA, oB;
        oA.x = f2bf(aa0*inva); oA.y = f2bf(aa1*inva); oA.z = f2bf(aa2*inva); oA.w = f2bf(aa3*inva);
        oB.x = f2bf(ab0*invb); oB.y = f2bf(ab1*invb); oB.z = f2bf(ab2*invb); oB.w = f2bf(ab3*invb);
        *(ushort4*)&Ml[lrow + quad*64 + l4*4] = oA;
        *(ushort4*)&Ml[lrow + (quad + 4)*64 + l4*4] = oB;
        if (j < 3){
            rb = rb_next;
            int ebn = __shfl(rb, 0);
            int dgn = __shfl(rb, 8) - ebn;
            idx = (lane < dgn) ? idxn : 0;
        }
    }
    __syncthreads();
    int m = l4;
    f32x4 acc = {};
#pragma unroll
    for (int kt = 0; kt < 18; ++kt){
        int kk = kt*32 + quad*8;
        bf16x8 a;
        if (kt < 16) a = *(const bf16x8*)&Ml[m*520 + kk];
        else         a = *(const bf16x8*)(xb + (size_t)(row0 + m)*64 + (kk - 512));
        bf16x8 b = *(const bf16x8*)(Wcat + (size_t)(w*16 + m)*576 + kk);
        acc = __builtin_amdgcn_mfma_f32_16x16x32_bf16(a, b, acc, 0, 0, 0);
    }
    int col = w*16 + m;
    float bz = bias[col];
#pragma unroll
    for (int i = 0; i < 4; ++i){
        int rr = row0 + quad*4 + i;
        h1pre[(size_t)rr*64 + col] = acc[i] + bz;
    }
}

// bn1 finalize: per-channel mean + rsqrt once (64 channels, one wave)
__global__ void bn1_finalize(const float* __restrict__ sums, const float* __restrict__ sumsq,
                             float* __restrict__ m1f, float* __restrict__ r1f){
    int c = threadIdx.x;
    if (c < 64){
        float m = sums[c] * INV_N;
        float v = sumsq[c] * INV_N - m*m;
        m1f[c] = m;
        r1f[c] = rsqrtf(fmaxf(v, 0.f) + BN_EPS);
    }
}

// ---------------------------------------------------------------------------
// MFMA GEMM 2 (R11): blockIdx.y = col-group (cg0: q+k, cg1: v+skip);
// bn1+leaky+residual fused in prologue (uses precomputed m1f/r1f —
// bit-identical to bn_apply1). One LDS plane/wave reused sequentially
// (pack->store->pack->store, same-wave DS ordering). All full-line stores.
// ---------------------------------------------------------------------------
#define QS 132   // LDS row stride (ushorts)
__global__ __launch_bounds__(256) void gemm_qkvs(const float* __restrict__ h1pre,
                                                 const float* __restrict__ nf,
                                                 const float* __restrict__ m1f, const float* __restrict__ r1f,
                                                 const float* __restrict__ g1, const float* __restrict__ b1,
                                                 const ushort_t* __restrict__ Wt2,
                                                 const float* __restrict__ bcat,
                                                 ushort_t* __restrict__ qb,
                                                 uchar_t* __restrict__ kb8,
                                                 ushort_t* __restrict__ vb,
                                                 ushort_t* __restrict__ sb){
    __shared__ ushort_t pl[4][16*QS];
    int w = threadIdx.x >> 6, lane = threadIdx.x & 63;
    int m = lane & 15, quad = lane >> 4;
    int r0 = blockIdx.x*64 + w*16;
    int cg = blockIdx.y;
    int row = r0 + m;
    bf16x8 afrag[2];
#pragma unroll
    for (int kt = 0; kt < 2; ++kt){
        int db = kt*32 + quad*8;
        bf16x8 f = (bf16x8){0,0,0,0,0,0,0,0};
        if (row < NN){
            float4 h0 = *(const float4*)(h1pre + (size_t)row*64 + db);
            float4 h1 = *(const float4*)(h1pre + (size_t)row*64 + db + 4);
            float4 n0 = *(const float4*)(nf + (size_t)row*64 + db);
            float4 n1 = *(const float4*)(nf + (size_t)row*64 + db + 4);
            float hh[8] = {h0.x,h0.y,h0.z,h0.w,h1.x,h1.y,h1.z,h1.w};
            float nn[8] = {n0.x,n0.y,n0.z,n0.w,n1.x,n1.y,n1.z,n1.w};
#pragma unroll
            for (int e = 0; e < 8; ++e){
                int c = db + e;
                float y = (hh[e] - m1f[c]) * r1f[c] * g1[c] + b1[c];
                y = (y >= 0.f) ? y : 0.01f*y;
                f[e] = (short)f2bf(y + nn[e]);
            }
        }
        afrag[kt] = f;
    }
    f32x4 acc[16] = {};
#pragma unroll
    for (int kt = 0; kt < 2; ++kt){
        int kk = kt*32 + quad*8;
#pragma unroll
        for (int ct = 0; ct < 16; ++ct){
            int g = cg*256 + ct*16 + m;
            bf16x8 b = *(const bf16x8*)(Wt2 + (size_t)g*64 + kk);
            acc[ct] = __builtin_amdgcn_mfma_f32_16x16x32_bf16(afrag[kt], b, acc[ct], 0, 0, 0);
        }
    }
    // ---- half 0 (ct 0..7): cg0 -> q, cg1 -> v ----
#pragma unroll
    for (int ct = 0; ct < 8; ++ct){
        int g = cg*256 + ct*16 + m;
        float bz = bcat[g];
        int cc = g & 127;
#pragma unroll
        for (int i = 0; i < 4; ++i)
            pl[w][(quad*4 + i)*QS + cc] = f2bf(acc[ct][i] + bz);
    }
    if (cg == 0){
#pragma unroll
        for (int t = 0; t < 4; ++t){
            int u = t*64 + lane;
            int r = u >> 4, c = (u & 15)*8;
            int gr = r0 + r;
            if (gr < NN) *(uint4*)(qb + (size_t)gr*128 + c) = *(const uint4*)&pl[w][r*QS + c];
        }
    } else {
#pragma unroll
        for (int t = 0; t < 4; ++t){
            int u = t*64 + lane;
            int r = u >> 4, c = (u & 15)*8;
            int gr = r0 + r;
            if (gr < NN) *(uint4*)(vb + (size_t)gr*128 + c) = *(const uint4*)&pl[w][r*QS + c];
        }
    }
    // ---- half 1 (ct 8..15): cg0 -> k (fp8), cg1 -> skip ----
#pragma unroll
    for (int ct = 8; ct < 16; ++ct){
        int g = cg*256 + ct*16 + m;
        float bz = bcat[g];
        int cc = g & 127;
#pragma unroll
        for (int i = 0; i < 4; ++i)
            pl[w][(quad*4 + i)*QS + cc] = f2bf(acc[ct][i] + bz);
    }
    if (cg == 0){
#pragma unroll
        for (int t = 0; t < 4; ++t){
            int u = t*64 + lane;
            int r = u >> 4, c = (u & 15)*8;
            int gr = r0 + r;
            if (gr < NN){
                uint4 kk4 = *(const uint4*)&pl[w][r*QS + c];
                uint2 o;
                o.x = f4_to_fp8(bflo(kk4.x), bfhi(kk4.x), bflo(kk4.y), bfhi(kk4.y));
                o.y = f4_to_fp8(bflo(kk4.z), bfhi(kk4.z), bflo(kk4.w), bfhi(kk4.w));
                *(uint2*)(kb8 + (size_t)gr*128 + c) = o;
            }
        }
    } else {
#pragma unroll
        for (int t = 0; t < 4; ++t){
            int u = t*64 + lane;
            int r = u >> 4, c = (u & 15)*8;
            int gr = r0 + r;
            if (gr < NN) *(uint4*)(sb + (size_t)gr*128 + c) = *(const uint4*)&pl[w][r*QS + c];
        }
    }
}

// ---------------------------------------------------------------------------
// MFMA GEMM 3: h3 = [x2b | nmeanb](50000x256) @ Wsage^T + bl   (32 cols)
// ---------------------------------------------------------------------------
__global__ __launch_bounds__(256) void sage_gemm(const ushort_t* __restrict__ x2b,
                                                 const ushort_t* __restrict__ nmeanb,
                                                 const ushort_t* __restrict__ Wsage,
                                                 const float* __restrict__ bl,
                                                 float* __restrict__ h3){
    int wv = threadIdx.x >> 6, lane = threadIdx.x & 63;
    int r0 = blockIdx.x*64 + wv*16;
    int m = lane & 15, quad = lane >> 4;
    int row = r0 + m;
    f32x4 acc[2] = {};
#pragma unroll
    for (int kt = 0; kt < 8; ++kt){
        int kk = kt*32 + quad*8;
        bf16x8 a;
        if (row < NN){
            const ushort_t* ap = (kt < 4) ? (x2b + (size_t)row*128 + kk)
                                          : (nmeanb + (size_t)row*128 + (kk - 128));
            a = *(const bf16x8*)ap;
        } else {
            a = (bf16x8){0,0,0,0,0,0,0,0};
        }
#pragma unroll
        for (int ct = 0; ct < 2; ++ct){
            bf16x8 b = *(const bf16x8*)(Wsage + (size_t)(ct*16 + m)*256 + kk);
            acc[ct] = __builtin_amdgcn_mfma_f32_16x16x32_bf16(a, b, acc[ct], 0, 0, 0);
        }
    }
#pragma unroll
    for (int ct = 0; ct < 2; ++ct){
        int col = ct*16 + m;
        float bz = bl[col];
#pragma unroll
        for (int i = 0; i < 4; ++i){
            int rr = r0 + quad*4 + i;
            if (rr < NN) h3[(size_t)rr*32 + col] = acc[ct][i] + bz;
        }
    }
}

// ---------------------------------------------------------------------------
// BatchNorm stats (dense layouts)
// ---------------------------------------------------------------------------
template<int C>
__global__ __launch_bounds__(256) void bn_stats(const float* __restrict__ X, int ld,
                                                float* __restrict__ sums, float* __restrict__ sumsq){
    __shared__ float s1[256], s2[256];
    int t = threadIdx.x;
    int c = t & (C-1);
    const int rpb = 256 / C;
    int r = blockIdx.x * rpb + (t / C);
    int rstride = gridDim.x * rpb;
    float a = 0.f, b = 0.f;
    for (; r < NN; r += rstride){
        float v = X[(size_t)r*ld + c];
        a += v; b += v*v;
    }
    s1[t] = a; s2[t] = b;
    __syncthreads();
    for (int off = 128; off >= C; off >>= 1){
        if (t < off){ s1[t] += s1[t+off]; s2[t] += s2[t+off]; }
        __syncthreads();
    }
    if (t < C){ atomicAdd(&sums[t], s1[t]); atomicAdd(&sumsq[t], s2[t]); }
}

__device__ __forceinline__ float bn_leaky(float z, float m, float rsv, float g, float b){
    float y = (z - m) * rsv * g + b;
    return y >= 0.f ? y : 0.01f * y;
}

// x2 = leaky(bn2(h2)) + (c<64 ? x1 : 0); -> bf16 x2b, fp8 x28, cols<32 fp32 x2r
__global__ void bn_apply2(const float* __restrict__ h2, const float* __restrict__ h1pre,
                          const float* __restrict__ nf,
                          const float* __restrict__ g1, const float* __restrict__ b1,
                          const float* __restrict__ s1, const float* __restrict__ q1,
                          const float* __restrict__ g2, const float* __restrict__ b2,
                          const float* __restrict__ s2, const float* __restrict__ q2,
                          float* __restrict__ x2r, ushort_t* __restrict__ x2b,
                          uchar_t* __restrict__ x28){
    int i = blockIdx.x*256 + threadIdx.x;
    if (i >= NN*128) return;
    int n = i >> 7, c = i & 127;
    float m2 = s2[c] * INV_N;
    float v2 = q2[c] * INV_N - m2*m2;
    float rsv2 = rsqrtf(fmaxf(v2, 0.f) + BN_EPS);
    float val = bn_leaky(h2[i], m2, rsv2, g2[c], b2[c]);
    if (c < 64){
        float m1 = s1[c] * INV_N;
        float v1 = q1[c] * INV_N - m1*m1;
        float rsv1 = rsqrtf(fmaxf(v1, 0.f) + BN_EPS);
        val += bn_leaky(h1pre[(size_t)n*64 + c], m1, rsv1, g1[c], b1[c]) + nf[(size_t)n*64 + c];
    }
    if (c < 32) x2r[(size_t)n*32 + c] = val;
    x2b[i] = f2bf(val);
    int p = __builtin_amdgcn_cvt_pk_fp8_f32(val, val, 0, false);
    x28[i] = (uchar_t)(p & 0xFF);
}

__global__ void bn_apply3(const float* __restrict__ h3, const float* __restrict__ x2r,
                          const float* __restrict__ g, const float* __restrict__ b,
                          const float* __restrict__ sums, const float* __restrict__ sumsq,
                          float* __restrict__ out){
    int i = blockIdx.x*256 + threadIdx.x;
    if (i >= NN*32) return;
    int c = i & 31;
    float m = sums[c] * INV_N;
    float v = sumsq[c] * INV_N - m*m;
    float rsv = rsqrtf(fmaxf(v, 0.f) + BN_EPS);
    out[i] = bn_leaky(h3[i], m, rsv, g[c], b[c]) + x2r[i];
}

// ---------------------------------------------------------------------------
// Attention: wave per dst node, CSR prefetch, 4 edges per half-wave in
// flight. k gathered as fp8 (4 B/lane), v as bf16 (8 B/lane) — 384 B/edge.
// Writes h2 = sb (skip) + attention output for ALL nodes.
// ---------------------------------------------------------------------------
__global__ __launch_bounds__(256) void attn_kernel(const ushort_t* __restrict__ qb,
                                                   const uchar_t* __restrict__ kb8,
                                                   const ushort_t* __restrict__ vb,
                                                   const ushort_t* __restrict__ sb,
                                                   const int* __restrict__ rs,
                                                   const int* __restrict__ csr,
                                                   float* __restrict__ h2){
    int w = threadIdx.x >> 6, lane = threadIdx.x & 63;
    int n = blockIdx.x*4 + w;
    if (n >= NN) return;
    int half = lane >> 5, l5 = lane & 31;
    int e0 = rs[n*8], e1 = rs[n*8 + 8];
    int deg = e1 - e0;
    uint2 qu = *(const uint2*)(qb + (size_t)n*128 + l5*4);
    uint2 sbv = *(const uint2*)(sb + (size_t)n*128 + l5*4);
    float q0 = bflo(qu.x), q1 = bfhi(qu.x), q2 = bflo(qu.y), q3 = bfhi(qu.y);
    const float scale = 0.17677669529663687f;   // 1/sqrt(32)
    int idx = 0;
    if (lane < deg) idx = csr[e0 + lane];
    int dcap = min(deg, 64);
    int nt = (dcap + 7) >> 3;
    float den = 0.f, a0 = 0.f, a1 = 0.f, a2 = 0.f, a3 = 0.f;
    for (int t = 0; t < nt; ++t){
        int i2 = t*8 + half*4;
        int j0 = i2, j1 = i2+1, j2 = i2+2, j3 = i2+3;
        bool v0 = j0 < dcap, v1 = j1 < dcap, v2 = j2 < dcap, v3 = j3 < dcap;
        int s0 = __shfl(idx, j0 & 63); s0 = v0 ? s0 : 0;
        int s1 = __shfl(idx, j1 & 63); s1 = v1 ? s1 : 0;
        int s2 = __shfl(idx, j2 & 63); s2 = v2 ? s2 : 0;
        int s3 = __shfl(idx, j3 & 63); s3 = v3 ? s3 : 0;
        unsigned int ku0 = *(const unsigned int*)(kb8 + (size_t)s0*128 + l5*4);
        unsigned int ku1 = *(const unsigned int*)(kb8 + (size_t)s1*128 + l5*4);
        unsigned int ku2 = *(const unsigned int*)(kb8 + (size_t)s2*128 + l5*4);
        unsigned int ku3 = *(const unsigned int*)(kb8 + (size_t)s3*128 + l5*4);
        uint2 vv0 = *(const uint2*)(vb + (size_t)s0*128 + l5*4);
        uint2 vv1 = *(const uint2*)(vb + (size_t)s1*128 + l5*4);
        uint2 vv2 = *(const uint2*)(vb + (size_t)s2*128 + l5*4);
        uint2 vv3 = *(const uint2*)(vb + (size_t)s3*128 + l5*4);
        float ka, kb_, kc, kd;
        fp8_to_f4(ku0, ka, kb_, kc, kd);
        float p0 = q0*ka + q1*kb_ + q2*kc + q3*kd;
        fp8_to_f4(ku1, ka, kb_, kc, kd);
        float p1 = q0*ka + q1*kb_ + q2*kc + q3*kd;
        fp8_to_f4(ku2, ka, kb_, kc, kd);
        float p2 = q0*ka + q1*kb_ + q2*kc + q3*kd;
        fp8_to_f4(ku3, ka, kb_, kc, kd);
        float p3 = q0*ka + q1*kb_ + q2*kc + q3*kd;
        p0 += __shfl_xor(p0, 1); p1 += __shfl_xor(p1, 1); p2 += __shfl_xor(p2, 1); p3 += __shfl_xor(p3, 1);
        p0 += __shfl_xor(p0, 2); p1 += __shfl_xor(p1, 2); p2 += __shfl_xor(p2, 2); p3 += __shfl_xor(p3, 2);
        p0 += __shfl_xor(p0, 4); p1 += __shfl_xor(p1, 4); p2 += __shfl_xor(p2, 4); p3 += __shfl_xor(p3, 4);
        float w0 = v0 ? __expf(p0 * scale) : 0.f;
        float w1 = v1 ? __expf(p1 * scale) : 0.f;
        float w2 = v2 ? __expf(p2 * scale) : 0.f;
        float w3 = v3 ? __expf(p3 * scale) : 0.f;
        den += w0 + w1 + w2 + w3;
        a0 += w0*bflo(vv0.x) + w1*bflo(vv1.x) + w2*bflo(vv2.x) + w3*bflo(vv3.x);
        a1 += w0*bfhi(vv0.x) + w1*bfhi(vv1.x) + w2*bfhi(vv2.x) + w3*bfhi(vv3.x);
        a2 += w0*bflo(vv0.y) + w1*bflo(vv1.y) + w2*bflo(vv2.y) + w3*bflo(vv3.y);
        a3 += w0*bfhi(vv0.y) + w1*bfhi(vv1.y) + w2*bfhi(vv2.y) + w3*bfhi(vv3.y);
    }
    // tail: deg > 64 (rare). Half-uniform trip counts; shuffles stay in-half.
    for (int e = 64 + half; e < deg; e += 2){
        int s = csr[e0 + e];
        unsigned int ku = *(const unsigned int*)(kb8 + (size_t)s*128 + l5*4);
        uint2 vv = *(const uint2*)(vb + (size_t)s*128 + l5*4);
        float ka, kb_, kc, kd;
        fp8_to_f4(ku, ka, kb_, kc, kd);
        float p = q0*ka + q1*kb_ + q2*kc + q3*kd;
        p += __shfl_xor(p, 1);
        p += __shfl_xor(p, 2);
        p += __shfl_xor(p, 4);
        float wg = __expf(p * scale);
        den += wg;
        a0 += wg*bflo(vv.x); a1 += wg*bfhi(vv.x);
        a2 += wg*bflo(vv.y); a3 += wg*bfhi(vv.y);
    }
    den += __shfl_xor(den, 32);
    a0 += __shfl_xor(a0, 32); a1 += __shfl_xor(a1, 32);
    a2 += __shfl_xor(a2, 32); a3 += __shfl_xor(a3, 32);
    if (half == 0){
        float inv = (den > 0.f) ? 1.f/den : 0.f;
        float4 o;
        o.x = bflo(sbv.x) + a0*inv;
        o.y = bfhi(sbv.x) + a1*inv;
        o.z = bflo(sbv.y) + a2*inv;
        o.w = bfhi(sbv.y) + a3*inv;
        *(float4*)(h2 + (size_t)n*128 + l5*4) = o;
    }
}

// ---------------------------------------------------------------------------
// SAGE mean aggregation: CSR prefetch, 4 edges/half, fp8 gathers (4 B/lane)
// ---------------------------------------------------------------------------
__global__ __launch_bounds__(256) void sage_agg(const uchar_t* __restrict__ x28,
                                                const int* __restrict__ rs,
                                                const int* __restrict__ csr,
                                                ushort_t* __restrict__ nmeanb){
    int w = threadIdx.x >> 6, lane = threadIdx.x & 63;
    int n = blockIdx.x*4 + w;
    if (n >= NN) return;
    int half = lane >> 5, l5 = lane & 31;
    int e0 = rs[n*8], e1 = rs[n*8 + 8];
    int deg = e1 - e0;
    int idx = 0;
    if (lane < deg) idx = csr[e0 + lane];
    int dcap = min(deg, 64);
    int nt = (dcap + 7) >> 3;
    float a0 = 0.f, a1 = 0.f, a2 = 0.f, a3 = 0.f;
    for (int t = 0; t < nt; ++t){
        int i2 = t*8 + half*4;
        int j0 = i2, j1 = i2+1, j2 = i2+2, j3 = i2+3;
        bool v0 = j0 < dcap, v1 = j1 < dcap, v2 = j2 < dcap, v3 = j3 < dcap;
        int s0 = __shfl(idx, j0 & 63); s0 = v0 ? s0 : 0;
        int s1 = __shfl(idx, j1 & 63); s1 = v1 ? s1 : 0;
        int s2 = __shfl(idx, j2 & 63); s2 = v2 ? s2 : 0;
        int s3 = __shfl(idx, j3 & 63); s3 = v3 ? s3 : 0;
        unsigned int u0 = *(const unsigned int*)(x28 + (size_t)s0*128 + l5*4);
        unsigned int u1 = *(const unsigned int*)(x28 + (size_t)s1*128 + l5*4);
        unsigned int u2 = *(const unsigned int*)(x28 + (size_t)s2*128 + l5*4);
        unsigned int u3 = *(const unsigned int*)(x28 + (size_t)s3*128 + l5*4);
        float fa, fb, fc, fd;
        if (v0){ fp8_to_f4(u0, fa, fb, fc, fd); a0 += fa; a1 += fb; a2 += fc; a3 += fd; }
        if (v1){ fp8_to_f4(u1, fa, fb, fc, fd); a0 += fa; a1 += fb; a2 += fc; a3 += fd; }
        if (v2){ fp8_to_f4(u2, fa, fb, fc, fd); a0 += fa; a1 += fb; a2 += fc; a3 += fd; }
        if (v3){ fp8_to_f4(u3, fa, fb, fc, fd); a0 += fa; a1 += fb; a2 += fc; a3 += fd; }
    }
    for (int e = 64 + half; e < deg; e += 2){
        int s = csr[e0 + e];
        unsigned int u = *(const unsigned int*)(x28 + (size_t)s*128 + l5*4);
        float fa, fb, fc, fd;
        fp8_to_f4(u, fa, fb, fc, fd);
        a0 += fa; a1 += fb; a2 += fc; a3 += fd;
    }
    a0 += __shfl_xor(a0, 32); a1 += __shfl_xor(a1, 32);
    a2 += __shfl_xor(a2, 32); a3 += __shfl_xor(a3, 32);
    if (half == 0){
        float inv = 1.f / fmaxf((float)deg, 1.f);
        ushort4 o;
        o.x = f2bf(a0*inv); o.y = f2bf(a1*inv); o.z = f2bf(a2*inv); o.w = f2bf(a3*inv);
        *(ushort4*)(nmeanb + (size_t)n*128 + l5*4) = o;
    }
}

// ---------------------------------------------------------------------------
extern "C" void kernel_launch(void* const* d_in, const int* in_sizes, int n_in,
                              void* d_out, int out_size, void* d_ws, size_t ws_size,
                              hipStream_t stream){
    const float* nf      = (const float*)d_in[0];
    const int*   ei      = (const int*)d_in[2];
    const int*   et      = (const int*)d_in[3];
    const float* rgcn_w  = (const float*)d_in[4];
    const float* root    = (const float*)d_in[5];
    const float* rbias   = (const float*)d_in[6];
    const float* bn1g    = (const float*)d_in[7];
    const float* bn1b    = (const float*)d_in[8];
    const float* wq      = (const float*)d_in[9];
    const float* bq      = (const float*)d_in[10];
    const float* wk      = (const float*)d_in[11];
    const float* bk      = (const float*)d_in[12];
    const float* wv      = (const float*)d_in[13];
    const float* bv      = (const float*)d_in[14];
    const float* wsk     = (const float*)d_in[15];
    const float* bsk     = (const float*)d_in[16];
    const float* bn2g    = (const float*)d_in[17];
    const float* bn2b    = (const float*)d_in[18];
    const float* wl      = (const float*)d_in[19];
    const float* bl      = (const float*)d_in[20];
    const float* wr      = (const float*)d_in[21];
    const float* bn3g    = (const float*)d_in[22];
    const float* bn3b    = (const float*)d_in[23];
    float* out = (float*)d_out;

    // ---- workspace carve (256B aligned) ----
    char* base = (char*)d_ws;
    size_t off = 0;
    auto take = [&](size_t bytes) -> char* {
        char* p = base + off;
        off += (bytes + 255) & ~(size_t)255;
        return p;
    };
    int*      deg    = (int*)take((size_t)NR*4);
    int*      rs     = (int*)take((size_t)(NR+1)*4);
    int*      tmp    = (int*)take((size_t)NR*4);
    int*      bsum   = (int*)take(1024*4);
    int*      cursor = (int*)take((size_t)NR*4);
    int*      csr    = (int*)take((size_t)NE*4);
    float*    bns    = (float*)take(1024*4);
    char*     zend   = base + off;                     // zero [deg, zend) in one memset
    ushort_t* Wcat   = (ushort_t*)take(64*576*2);
    ushort_t* Wt2    = (ushort_t*)take(512*64*2);
    float*    bcat   = (float*)take(512*4);
    ushort_t* Wsage  = (ushort_t*)take(32*256*2);
    ushort_t* xb     = (ushort_t*)take((size_t)NN*64*2);
    uchar_t*  xb8    = (uchar_t*)take((size_t)NN*64);       // fp8 gather copy (3.2 MB)
    float*    h1pre  = (float*)take((size_t)NN*64*4);
    float*    h2     = (float*)take((size_t)NN*128*4);
    float*    x2r    = (float*)take((size_t)NN*32*4);
    ushort_t* sb     = (ushort_t*)take((size_t)NN*128*2);   // bf16 skip (12.8 MB)
    char*     bigA   = take((size_t)NN*512*2);              // 51.2 MB multi-use
    if (off > ws_size) return;

    // bigA aliases (byte offsets); lifetimes verified stage-by-stage:
    ushort_t* qb     = (ushort_t*)(bigA + (size_t)NN*128);       // gemm_qkvs -> attn (12.8 MB)
    ushort_t* vb     = (ushort_t*)(bigA + (size_t)NN*384);       // gemm_qkvs -> attn (12.8 MB)
    uchar_t*  kb8    = (uchar_t*)(bigA + (size_t)NN*640);        // gemm_qkvs -> attn (6.4 MB)
    ushort_t* x2b    = (ushort_t*)bigA;                          // bn_apply2 -> sage_gemm (12.8 MB)
    uchar_t*  x28    = (uchar_t*)(bigA + (size_t)NN*256);        // bn_apply2 -> sage_agg (6.4 MB)
    ushort_t* nmeanb = (ushort_t*)(bigA + (size_t)NN*512);       // sage_agg -> sage_gemm (12.8 MB)
    float*    h3     = (float*)(bigA + (size_t)NN*768);          // sage_gemm -> bn3 (6.4 MB)

    hipMemsetAsync(deg, 0, (size_t)(zend - (char*)deg), stream); // deg+cursor+bns (rest harmless)

    // ---- CSR build (relation-bucketed) + weight prep ----
    const int PREP_N = NN*16 + 64*576 + 512*64 + 512 + 32*256;
    k_prep <<<(PREP_N+255)/256, 256, 0, stream>>>(nf, rgcn_w, root, wq, wk, wv, wsk,
                                                  bq, bk, bv, bsk, wl, wr,
                                                  xb, xb8, Wcat, Wt2, bcat, Wsage);
    k_deg  <<<(NE+255)/256, 256, 0, stream>>>(ei, et, deg);
    k_scan1<<<NB2, SCAN_BS, 0, stream>>>(deg, tmp, bsum);
    k_scan2<<<1, 1024, 0, stream>>>(bsum);
    k_scan3<<<(NR+255)/256, 256, 0, stream>>>(tmp, bsum, rs);
    k_fill <<<(NE+255)/256, 256, 0, stream>>>(ei, et, rs, cursor, csr);

    const int NB4 = (NN + 3) / 4;
    const int NBG = (NN + 63) / 64;

    // ---- stage 1: RGCN (fused agg + MFMA) ----
    rgcn_fused<<<NN/16, 256, 0, stream>>>(xb, xb8, rs, csr, Wcat, rbias, h1pre);
    bn_stats<64><<<256, 256, 0, stream>>>(h1pre, 64, bns + 0, bns + 64);
    bn1_finalize<<<1, 64, 0, stream>>>(bns + 0, bns + 64, bns + 448, bns + 512);

    // ---- stage 2: TransformerConv (bn1 fused into gemm_qkvs prologue) ----
    gemm_qkvs<<<dim3(NBG, 2), 256, 0, stream>>>(h1pre, nf, bns + 448, bns + 512, bn1g, bn1b,
                                                Wt2, bcat, qb, kb8, vb, sb);
    attn_kernel<<<NB4, 256, 0, stream>>>(qb, kb8, vb, sb, rs, csr, h2);
    bn_stats<128><<<256, 256, 0, stream>>>(h2, 128, bns + 128, bns + 256);
    bn_apply2<<<(NN*128+255)/256, 256, 0, stream>>>(h2, h1pre, nf,
                                                    bn1g, bn1b, bns + 0, bns + 64,
                                                    bn2g, bn2b, bns + 128, bns + 256,
                                                    x2r, x2b, x28);

    // ---- stage 3: SAGE ----
    sage_agg<<<NB4, 256, 0, stream>>>(x28, rs, csr, nmeanb);
    sage_gemm<<<NBG, 256, 0, stream>>>(x2b, nmeanb, Wsage, bl, h3);
    bn_stats<32><<<256, 256, 0, stream>>>(h3, 32, bns + 384, bns + 416);
    bn_apply3<<<(NN*32+255)/256, 256, 0, stream>>>(h3, x2r, bn3g, bn3b, bns + 384, bns + 416, out);
}

// Round 12
// 430.466 us; speedup vs baseline: 1.0582x; 1.0582x over previous
//
#include <hip/hip_runtime.h>
#include <stdint.h>

#define NN 50000
#define NE 800000
#define NR (NN*8)            // (node, relation) segments
#define SCAN_BS 512
#define NB2 782              // ceil(NR/512)
#define INV_N (1.0f/50000.0f)
#define BN_EPS 1e-5f

typedef unsigned short ushort_t;
typedef unsigned char uchar_t;
typedef short bf16x8 __attribute__((ext_vector_type(8)));   // 8 bf16 (4 VGPRs)
typedef float f32x4 __attribute__((ext_vector_type(4)));
typedef float f32x2 __attribute__((ext_vector_type(2)));

__device__ __forceinline__ ushort_t f2bf(float f){
    unsigned int u = __float_as_uint(f);
    u += 0x7FFFu + ((u >> 16) & 1u);      // RNE
    return (ushort_t)(u >> 16);
}
__device__ __forceinline__ float bf2f(ushort_t h){ return __uint_as_float(((unsigned int)h) << 16); }
__device__ __forceinline__ float bflo(unsigned int u){ return __uint_as_float(u << 16); }
__device__ __forceinline__ float bfhi(unsigned int u){ return __uint_as_float(u & 0xFFFF0000u); }

// fp8 e4m3 (OCP) helpers via HW converters
__device__ __forceinline__ unsigned int f4_to_fp8(float a, float b, float c, float d){
    int v = __builtin_amdgcn_cvt_pk_fp8_f32(a, b, 0, false);
    v = __builtin_amdgcn_cvt_pk_fp8_f32(c, d, v, true);
    return (unsigned int)v;
}
__device__ __forceinline__ void fp8_to_f4(unsigned int u, float& a, float& b, float& c, float& d){
    f32x2 lo = __builtin_amdgcn_cvt_pk_f32_fp8(u, false);
    f32x2 hi = __builtin_amdgcn_cvt_pk_f32_fp8(u, true);
    a = lo.x; b = lo.y; c = hi.x; d = hi.y;
}

// ---------------------------------------------------------------------------
// CSR build over (dst, relation) segments
// ---------------------------------------------------------------------------
__global__ void k_deg(const int* __restrict__ ei, const int* __restrict__ et, int* __restrict__ deg){
    int e = blockIdx.x*256 + threadIdx.x;
    if (e < NE) atomicAdd(&deg[ei[NE + e]*8 + et[e]], 1);
}

__global__ void k_scan1(const int* __restrict__ deg, int* __restrict__ tmp, int* __restrict__ bsum){
    __shared__ int s[SCAN_BS];
    int t = threadIdx.x;
    int i = blockIdx.x*SCAN_BS + t;
    s[t] = (i < NR) ? deg[i] : 0;
    __syncthreads();
    for (int off = 1; off < SCAN_BS; off <<= 1){
        int add = (t >= off) ? s[t-off] : 0;
        __syncthreads();
        s[t] += add;
        __syncthreads();
    }
    if (i < NR) tmp[i] = s[t];
    if (t == SCAN_BS-1) bsum[blockIdx.x] = s[t];
}

__global__ void k_scan2(int* __restrict__ bsum){
    __shared__ int s[NB2];
    int t = threadIdx.x;
    if (t < NB2) s[t] = bsum[t];
    __syncthreads();
    if (t == 0){
        int acc = 0;
        for (int i = 0; i < NB2; ++i){ acc += s[i]; s[i] = acc; }
    }
    __syncthreads();
    if (t < NB2) bsum[t] = s[t];
}

__global__ void k_scan3(const int* __restrict__ tmp, const int* __restrict__ bsum, int* __restrict__ rs){
    int i = blockIdx.x*256 + threadIdx.x;
    if (i < NR){
        int b = i >> 9;
        int off = (b > 0) ? bsum[b-1] : 0;
        rs[i+1] = tmp[i] + off;
        if (i == 0) rs[0] = 0;
    }
}

__global__ void k_fill(const int* __restrict__ ei, const int* __restrict__ et,
                       const int* __restrict__ rs, int* __restrict__ cursor, int* __restrict__ csr){
    int e = blockIdx.x*256 + threadIdx.x;
    if (e < NE){
        int seg = ei[NE + e]*8 + et[e];
        int pos = atomicAdd(&cursor[seg], 1);
        csr[rs[seg] + pos] = ei[e];
    }
}

// ---------------------------------------------------------------------------
// Prep: cast nf->bf16 (xb) + fp8 (xb8), bf16 weight tables, concat biases
// ---------------------------------------------------------------------------
__global__ void k_prep(const float* __restrict__ nf,
                       const float* __restrict__ rgcn_w, const float* __restrict__ root,
                       const float* __restrict__ wq, const float* __restrict__ wk,
                       const float* __restrict__ wv, const float* __restrict__ wsk,
                       const float* __restrict__ bq, const float* __restrict__ bk,
                       const float* __restrict__ bv, const float* __restrict__ bsk,
                       const float* __restrict__ wl, const float* __restrict__ wr,
                       ushort_t* __restrict__ xb, uchar_t* __restrict__ xb8,
                       ushort_t* __restrict__ Wcat,
                       ushort_t* __restrict__ Wt2, float* __restrict__ bcat,
                       ushort_t* __restrict__ Wsage){
    int i = blockIdx.x*256 + threadIdx.x;
    const int NXB = NN*16;
    if (i < NXB){
        float4 v = ((const float4*)nf)[i];
        ushort4 h;
        h.x = f2bf(v.x); h.y = f2bf(v.y); h.z = f2bf(v.z); h.w = f2bf(v.w);
        ((ushort4*)xb)[i] = h;
        ((unsigned int*)xb8)[i] = f4_to_fp8(v.x, v.y, v.z, v.w);
        return;
    }
    int j = i - NXB;
    if (j < 64*576){
        int h = j / 576, k = j - h*576;
        float v = (k < 512) ? rgcn_w[(size_t)k*64 + h] : root[(size_t)(k-512)*64 + h];
        Wcat[j] = f2bf(v);
    } else if (j < 64*576 + 512*64){
        int jj = j - 64*576;
        int c = jj >> 6, k = jj & 63;
        int mt = c >> 7, cc = c & 127;
        const float* W = (mt==0)?wq:(mt==1)?wk:(mt==2)?wv:wsk;
        Wt2[jj] = f2bf(W[(size_t)k*128 + cc]);
    } else if (j < 64*576 + 512*64 + 512){
        int c = j - (64*576 + 512*64);
        int mt = c >> 7, cc = c & 127;
        const float* B = (mt==0)?bq:(mt==1)?bk:(mt==2)?bv:bsk;
        bcat[c] = B[cc];
    } else if (j < 64*576 + 512*64 + 512 + 32*256){
        int jj = j - (64*576 + 512*64 + 512);
        int c = jj >> 8, k = jj & 255;
        float v = (k < 128) ? wr[(size_t)k*32 + c] : wl[(size_t)(k-128)*32 + c];
        Wsage[jj] = f2bf(v);
    }
}

// ---------------------------------------------------------------------------
// FUSED RGCN. Phase 1: quad owns relations {quad,quad+4} (4 gathers in
// flight/lane); node j+1's rs row + csr chunk issued BEFORE node j's gather
// loop (prefetch addr depends only on current rb). Phase 2: 16x64 MFMA, K=576.
// ---------------------------------------------------------------------------
__global__ __launch_bounds__(256) void rgcn_fused(const ushort_t* __restrict__ xb,
                                                  const uchar_t* __restrict__ xb8,
                                                  const int* __restrict__ rs,
                                                  const int* __restrict__ csr,
                                                  const ushort_t* __restrict__ Wcat,
                                                  const float* __restrict__ bias,
                                                  float* __restrict__ h1pre){
    __shared__ ushort_t Ml[16*520];
    int w = threadIdx.x >> 6, lane = threadIdx.x & 63;
    int quad = lane >> 4, l4 = lane & 15;
    int row0 = blockIdx.x * 16;                 // 3125*16 == 50000 exactly
    int n0 = row0 + w*4;
    int rsel = (lane < 9 ? lane : 8);
    int rb = rs[n0*8 + rsel];
    int eb0 = __shfl(rb, 0);
    int dg0 = __shfl(rb, 8) - eb0;
    int idx = (lane < dg0) ? csr[eb0 + lane] : 0;
    for (int j = 0; j < 4; ++j){
        int lrow = (w*4 + j)*520;
        int ebase = __shfl(rb, 0);
        int enext = __shfl(rb, 8);
        int rb_next = 0, idxn = 0;
        if (j < 3){
            rb_next = rs[(n0 + j + 1)*8 + rsel];
            idxn = csr[min(enext + lane, NE - 1)];   // addr independent of rb_next
        }
        int e0a = __shfl(rb, quad),     e1a = __shfl(rb, quad + 1);
        int e0b = __shfl(rb, quad + 4), e1b = __shfl(rb, quad + 5);
        int oa = e0a - ebase, la = e1a - e0a;
        int ob = e0b - ebase, lb = e1b - e0b;
        int ml = max(la, lb);
        ml = max(ml, __shfl_xor(ml, 16));
        ml = max(ml, __shfl_xor(ml, 32));
        float aa0=0.f, aa1=0.f, aa2=0.f, aa3=0.f;
        float ab0=0.f, ab1=0.f, ab2=0.f, ab3=0.f;
        for (int i = 0; i < ml; i += 2){
            int jA0 = oa + i, jA1 = oa + i + 1;
            int jB0 = ob + i, jB1 = ob + i + 1;
            bool vA0 = i < la, vA1 = i + 1 < la;
            bool vB0 = i < lb, vB1 = i + 1 < lb;
            int sA0 = __shfl(idx, jA0 & 63);
            int sA1 = __shfl(idx, jA1 & 63);
            int sB0 = __shfl(idx, jB0 & 63);
            int sB1 = __shfl(idx, jB1 & 63);
            if (jA0 >= 64 && vA0) sA0 = csr[ebase + jA0];   // rare (deg>64)
            if (jA1 >= 64 && vA1) sA1 = csr[ebase + jA1];
            if (jB0 >= 64 && vB0) sB0 = csr[ebase + jB0];
            if (jB1 >= 64 && vB1) sB1 = csr[ebase + jB1];
            sA0 = vA0 ? sA0 : 0; sA1 = vA1 ? sA1 : 0;
            sB0 = vB0 ? sB0 : 0; sB1 = vB1 ? sB1 : 0;
            unsigned int uA0 = *(const unsigned int*)(xb8 + (size_t)sA0*64 + l4*4);
            unsigned int uA1 = *(const unsigned int*)(xb8 + (size_t)sA1*64 + l4*4);
            unsigned int uB0 = *(const unsigned int*)(xb8 + (size_t)sB0*64 + l4*4);
            unsigned int uB1 = *(const unsigned int*)(xb8 + (size_t)sB1*64 + l4*4);
            float f0,f1,f2,f3;
            fp8_to_f4(uA0,f0,f1,f2,f3); if (vA0){ aa0+=f0; aa1+=f1; aa2+=f2; aa3+=f3; }
            fp8_to_f4(uA1,f0,f1,f2,f3); if (vA1){ aa0+=f0; aa1+=f1; aa2+=f2; aa3+=f3; }
            fp8_to_f4(uB0,f0,f1,f2,f3); if (vB0){ ab0+=f0; ab1+=f1; ab2+=f2; ab3+=f3; }
            fp8_to_f4(uB1,f0,f1,f2,f3); if (vB1){ ab0+=f0; ab1+=f1; ab2+=f2; ab3+=f3; }
        }
        float inva = 1.f / fmaxf((float)la, 1.f);
        float invb = 1.f / fmaxf((float)lb, 1.f);
        ushort4 oA, oB;
        oA.x = f2bf(aa0*inva); oA.y = f2bf(aa1*inva); oA.z = f2bf(aa2*inva); oA.w = f2bf(aa3*inva);
        oB.x = f2bf(ab0*invb); oB.y = f2bf(ab1*invb); oB.z = f2bf(ab2*invb); oB.w = f2bf(ab3*invb);
        *(ushort4*)&Ml[lrow + quad*64 + l4*4] = oA;
        *(ushort4*)&Ml[lrow + (quad + 4)*64 + l4*4] = oB;
        if (j < 3){
            rb = rb_next;
            int ebn = __shfl(rb, 0);
            int dgn = __shfl(rb, 8) - ebn;
            idx = (lane < dgn) ? idxn : 0;
        }
    }
    __syncthreads();
    int m = l4;
    f32x4 acc = {};
#pragma unroll
    for (int kt = 0; kt < 18; ++kt){
        int kk = kt*32 + quad*8;
        bf16x8 a;
        if (kt < 16) a = *(const bf16x8*)&Ml[m*520 + kk];
        else         a = *(const bf16x8*)(xb + (size_t)(row0 + m)*64 + (kk - 512));
        bf16x8 b = *(const bf16x8*)(Wcat + (size_t)(w*16 + m)*576 + kk);
        acc = __builtin_amdgcn_mfma_f32_16x16x32_bf16(a, b, acc, 0, 0, 0);
    }
    int col = w*16 + m;
    float bz = bias[col];
#pragma unroll
    for (int i = 0; i < 4; ++i){
        int rr = row0 + quad*4 + i;
        h1pre[(size_t)rr*64 + col] = acc[i] + bz;
    }
}

// bn1 finalize: fold to scale/shift: A = rsv*g, C = b - m*A  (one wave)
__global__ void bn1_finalize(const float* __restrict__ sums, const float* __restrict__ sumsq,
                             const float* __restrict__ g1, const float* __restrict__ b1,
                             float* __restrict__ A1, float* __restrict__ C1){
    int c = threadIdx.x;
    if (c < 64){
        float m = sums[c] * INV_N;
        float v = sumsq[c] * INV_N - m*m;
        float rsv = rsqrtf(fmaxf(v, 0.f) + BN_EPS);
        float A = rsv * g1[c];
        A1[c] = A;
        C1[c] = b1[c] - m * A;
    }
}

// ---------------------------------------------------------------------------
// MFMA GEMM 2 (R12): Wt2 col-group tile (256x64 bf16 = 32 KB) staged into
// LDS once per block — kills the 512 KB/block L1 B-fragment traffic (each of
// the 16 waves re-read the same 32 KB from L1). bn1 as scale/shift (A1/C1),
// loaded as float4. blockIdx.y = col-group; per-wave pl plane epilogue.
// ---------------------------------------------------------------------------
#define QS 132   // pl row stride (ushorts)
#define BS 68    // Bs row stride (ushorts): 2-way bank alias (free, m136)
__global__ __launch_bounds__(256) void gemm_qkvs(const float* __restrict__ h1pre,
                                                 const float* __restrict__ nf,
                                                 const float* __restrict__ A1, const float* __restrict__ C1,
                                                 const ushort_t* __restrict__ Wt2,
                                                 const float* __restrict__ bcat,
                                                 ushort_t* __restrict__ qb,
                                                 uchar_t* __restrict__ kb8,
                                                 ushort_t* __restrict__ vb,
                                                 ushort_t* __restrict__ sb){
    __shared__ ushort_t Bs[256*BS];
    __shared__ ushort_t pl[4][16*QS];
    int w = threadIdx.x >> 6, lane = threadIdx.x & 63;
    int m = lane & 15, quad = lane >> 4;
    int r0 = blockIdx.x*64 + w*16;
    int cg = blockIdx.y;
    int row = r0 + m;
    // ---- stage Wt2 col-group tile: 256 rows x 64 ush = 2048 uint4 ----
    {
        int t = threadIdx.x;
        const ushort_t* wsrc = Wt2 + (size_t)cg*256*64;
#pragma unroll
        for (int u0 = 0; u0 < 8; ++u0){
            int u = u0*256 + t;
            int r = u >> 3, c8 = (u & 7)*8;
            *(uint4*)&Bs[r*BS + c8] = *(const uint4*)(wsrc + u*8);
        }
    }
    // ---- prologue: x1 fragments = bf16(leaky(h*A+C) + nf) ----
    bf16x8 afrag[2];
#pragma unroll
    for (int kt = 0; kt < 2; ++kt){
        int db = kt*32 + quad*8;
        bf16x8 f = (bf16x8){0,0,0,0,0,0,0,0};
        if (row < NN){
            float4 h0 = *(const float4*)(h1pre + (size_t)row*64 + db);
            float4 h1 = *(const float4*)(h1pre + (size_t)row*64 + db + 4);
            float4 n0 = *(const float4*)(nf + (size_t)row*64 + db);
            float4 n1 = *(const float4*)(nf + (size_t)row*64 + db + 4);
            float4 a0 = *(const float4*)(A1 + db);
            float4 a1 = *(const float4*)(A1 + db + 4);
            float4 c0 = *(const float4*)(C1 + db);
            float4 c1 = *(const float4*)(C1 + db + 4);
            float hh[8] = {h0.x,h0.y,h0.z,h0.w,h1.x,h1.y,h1.z,h1.w};
            float nn[8] = {n0.x,n0.y,n0.z,n0.w,n1.x,n1.y,n1.z,n1.w};
            float AA[8] = {a0.x,a0.y,a0.z,a0.w,a1.x,a1.y,a1.z,a1.w};
            float CC[8] = {c0.x,c0.y,c0.z,c0.w,c1.x,c1.y,c1.z,c1.w};
#pragma unroll
            for (int e = 0; e < 8; ++e){
                float y = fmaf(hh[e], AA[e], CC[e]);
                y = (y >= 0.f) ? y : 0.01f*y;
                f[e] = (short)f2bf(y + nn[e]);
            }
        }
        afrag[kt] = f;
    }
    __syncthreads();
    f32x4 acc[16] = {};
#pragma unroll
    for (int kt = 0; kt < 2; ++kt){
        int kk = kt*32 + quad*8;
#pragma unroll
        for (int ct = 0; ct < 16; ++ct){
            bf16x8 b = *(const bf16x8*)&Bs[(size_t)(ct*16 + m)*BS + kk];
            acc[ct] = __builtin_amdgcn_mfma_f32_16x16x32_bf16(afrag[kt], b, acc[ct], 0, 0, 0);
        }
    }
    // ---- half 0 (ct 0..7): cg0 -> q, cg1 -> v ----
#pragma unroll
    for (int ct = 0; ct < 8; ++ct){
        int g = cg*256 + ct*16 + m;
        float bz = bcat[g];
        int cc = g & 127;
#pragma unroll
        for (int i = 0; i < 4; ++i)
            pl[w][(quad*4 + i)*QS + cc] = f2bf(acc[ct][i] + bz);
    }
    if (cg == 0){
#pragma unroll
        for (int t = 0; t < 4; ++t){
            int u = t*64 + lane;
            int r = u >> 4, c = (u & 15)*8;
            int gr = r0 + r;
            if (gr < NN) *(uint4*)(qb + (size_t)gr*128 + c) = *(const uint4*)&pl[w][r*QS + c];
        }
    } else {
#pragma unroll
        for (int t = 0; t < 4; ++t){
            int u = t*64 + lane;
            int r = u >> 4, c = (u & 15)*8;
            int gr = r0 + r;
            if (gr < NN) *(uint4*)(vb + (size_t)gr*128 + c) = *(const uint4*)&pl[w][r*QS + c];
        }
    }
    // ---- half 1 (ct 8..15): cg0 -> k (fp8), cg1 -> skip ----
#pragma unroll
    for (int ct = 8; ct < 16; ++ct){
        int g = cg*256 + ct*16 + m;
        float bz = bcat[g];
        int cc = g & 127;
#pragma unroll
        for (int i = 0; i < 4; ++i)
            pl[w][(quad*4 + i)*QS + cc] = f2bf(acc[ct][i] + bz);
    }
    if (cg == 0){
#pragma unroll
        for (int t = 0; t < 4; ++t){
            int u = t*64 + lane;
            int r = u >> 4, c = (u & 15)*8;
            int gr = r0 + r;
            if (gr < NN){
                uint4 kk4 = *(const uint4*)&pl[w][r*QS + c];
                uint2 o;
                o.x = f4_to_fp8(bflo(kk4.x), bfhi(kk4.x), bflo(kk4.y), bfhi(kk4.y));
                o.y = f4_to_fp8(bflo(kk4.z), bfhi(kk4.z), bflo(kk4.w), bfhi(kk4.w));
                *(uint2*)(kb8 + (size_t)gr*128 + c) = o;
            }
        }
    } else {
#pragma unroll
        for (int t = 0; t < 4; ++t){
            int u = t*64 + lane;
            int r = u >> 4, c = (u & 15)*8;
            int gr = r0 + r;
            if (gr < NN) *(uint4*)(sb + (size_t)gr*128 + c) = *(const uint4*)&pl[w][r*QS + c];
        }
    }
}

// ---------------------------------------------------------------------------
// MFMA GEMM 3: h3 = [x2b | nmeanb](50000x256) @ Wsage^T + bl   (32 cols)
// ---------------------------------------------------------------------------
__global__ __launch_bounds__(256) void sage_gemm(const ushort_t* __restrict__ x2b,
                                                 const ushort_t* __restrict__ nmeanb,
                                                 const ushort_t* __restrict__ Wsage,
                                                 const float* __restrict__ bl,
                                                 float* __restrict__ h3){
    int wv = threadIdx.x >> 6, lane = threadIdx.x & 63;
    int r0 = blockIdx.x*64 + wv*16;
    int m = lane & 15, quad = lane >> 4;
    int row = r0 + m;
    f32x4 acc[2] = {};
#pragma unroll
    for (int kt = 0; kt < 8; ++kt){
        int kk = kt*32 + quad*8;
        bf16x8 a;
        if (row < NN){
            const ushort_t* ap = (kt < 4) ? (x2b + (size_t)row*128 + kk)
                                          : (nmeanb + (size_t)row*128 + (kk - 128));
            a = *(const bf16x8*)ap;
        } else {
            a = (bf16x8){0,0,0,0,0,0,0,0};
        }
#pragma unroll
        for (int ct = 0; ct < 2; ++ct){
            bf16x8 b = *(const bf16x8*)(Wsage + (size_t)(ct*16 + m)*256 + kk);
            acc[ct] = __builtin_amdgcn_mfma_f32_16x16x32_bf16(a, b, acc[ct], 0, 0, 0);
        }
    }
#pragma unroll
    for (int ct = 0; ct < 2; ++ct){
        int col = ct*16 + m;
        float bz = bl[col];
#pragma unroll
        for (int i = 0; i < 4; ++i){
            int rr = r0 + quad*4 + i;
            if (rr < NN) h3[(size_t)rr*32 + col] = acc[ct][i] + bz;
        }
    }
}

// ---------------------------------------------------------------------------
// BatchNorm stats (dense layouts)
// ---------------------------------------------------------------------------
template<int C>
__global__ __launch_bounds__(256) void bn_stats(const float* __restrict__ X, int ld,
                                                float* __restrict__ sums, float* __restrict__ sumsq){
    __shared__ float s1[256], s2[256];
    int t = threadIdx.x;
    int c = t & (C-1);
    const int rpb = 256 / C;
    int r = blockIdx.x * rpb + (t / C);
    int rstride = gridDim.x * rpb;
    float a = 0.f, b = 0.f;
    for (; r < NN; r += rstride){
        float v = X[(size_t)r*ld + c];
        a += v; b += v*v;
    }
    s1[t] = a; s2[t] = b;
    __syncthreads();
    for (int off = 128; off >= C; off >>= 1){
        if (t < off){ s1[t] += s1[t+off]; s2[t] += s2[t+off]; }
        __syncthreads();
    }
    if (t < C){ atomicAdd(&sums[t], s1[t]); atomicAdd(&sumsq[t], s2[t]); }
}

__device__ __forceinline__ float bn_leaky(float z, float m, float rsv, float g, float b){
    float y = (z - m) * rsv * g + b;
    return y >= 0.f ? y : 0.01f * y;
}

// x2 = leaky(bn2(h2)) + (c<64 ? x1 : 0); -> bf16 x2b, fp8 x28, cols<32 fp32 x2r
__global__ void bn_apply2(const float* __restrict__ h2, const float* __restrict__ h1pre,
                          const float* __restrict__ nf,
                          const float* __restrict__ g1, const float* __restrict__ b1,
                          const float* __restrict__ s1, const float* __restrict__ q1,
                          const float* __restrict__ g2, const float* __restrict__ b2,
                          const float* __restrict__ s2, const float* __restrict__ q2,
                          float* __restrict__ x2r, ushort_t* __restrict__ x2b,
                          uchar_t* __restrict__ x28){
    int i = blockIdx.x*256 + threadIdx.x;
    if (i >= NN*128) return;
    int n = i >> 7, c = i & 127;
    float m2 = s2[c] * INV_N;
    float v2 = q2[c] * INV_N - m2*m2;
    float rsv2 = rsqrtf(fmaxf(v2, 0.f) + BN_EPS);
    float val = bn_leaky(h2[i], m2, rsv2, g2[c], b2[c]);
    if (c < 64){
        float m1 = s1[c] * INV_N;
        float v1 = q1[c] * INV_N - m1*m1;
        float rsv1 = rsqrtf(fmaxf(v1, 0.f) + BN_EPS);
        val += bn_leaky(h1pre[(size_t)n*64 + c], m1, rsv1, g1[c], b1[c]) + nf[(size_t)n*64 + c];
    }
    if (c < 32) x2r[(size_t)n*32 + c] = val;
    x2b[i] = f2bf(val);
    int p = __builtin_amdgcn_cvt_pk_fp8_f32(val, val, 0, false);
    x28[i] = (uchar_t)(p & 0xFF);
}

__global__ void bn_apply3(const float* __restrict__ h3, const float* __restrict__ x2r,
                          const float* __restrict__ g, const float* __restrict__ b,
                          const float* __restrict__ sums, const float* __restrict__ sumsq,
                          float* __restrict__ out){
    int i = blockIdx.x*256 + threadIdx.x;
    if (i >= NN*32) return;
    int c = i & 31;
    float m = sums[c] * INV_N;
    float v = sumsq[c] * INV_N - m*m;
    float rsv = rsqrtf(fmaxf(v, 0.f) + BN_EPS);
    out[i] = bn_leaky(h3[i], m, rsv, g[c], b[c]) + x2r[i];
}

// ---------------------------------------------------------------------------
// Attention: wave per dst node, CSR prefetch, 4 edges per half-wave in
// flight. k gathered as fp8 (4 B/lane), v as bf16 (8 B/lane) — 384 B/edge.
// Writes h2 = sb (skip) + attention output for ALL nodes.
// ---------------------------------------------------------------------------
__global__ __launch_bounds__(256) void attn_kernel(const ushort_t* __restrict__ qb,
                                                   const uchar_t* __restrict__ kb8,
                                                   const ushort_t* __restrict__ vb,
                                                   const ushort_t* __restrict__ sb,
                                                   const int* __restrict__ rs,
                                                   const int* __restrict__ csr,
                                                   float* __restrict__ h2){
    int w = threadIdx.x >> 6, lane = threadIdx.x & 63;
    int n = blockIdx.x*4 + w;
    if (n >= NN) return;
    int half = lane >> 5, l5 = lane & 31;
    int e0 = rs[n*8], e1 = rs[n*8 + 8];
    int deg = e1 - e0;
    uint2 qu = *(const uint2*)(qb + (size_t)n*128 + l5*4);
    uint2 sbv = *(const uint2*)(sb + (size_t)n*128 + l5*4);
    float q0 = bflo(qu.x), q1 = bfhi(qu.x), q2 = bflo(qu.y), q3 = bfhi(qu.y);
    const float scale = 0.17677669529663687f;   // 1/sqrt(32)
    int idx = 0;
    if (lane < deg) idx = csr[e0 + lane];
    int dcap = min(deg, 64);
    int nt = (dcap + 7) >> 3;
    float den = 0.f, a0 = 0.f, a1 = 0.f, a2 = 0.f, a3 = 0.f;
    for (int t = 0; t < nt; ++t){
        int i2 = t*8 + half*4;
        int j0 = i2, j1 = i2+1, j2 = i2+2, j3 = i2+3;
        bool v0 = j0 < dcap, v1 = j1 < dcap, v2 = j2 < dcap, v3 = j3 < dcap;
        int s0 = __shfl(idx, j0 & 63); s0 = v0 ? s0 : 0;
        int s1 = __shfl(idx, j1 & 63); s1 = v1 ? s1 : 0;
        int s2 = __shfl(idx, j2 & 63); s2 = v2 ? s2 : 0;
        int s3 = __shfl(idx, j3 & 63); s3 = v3 ? s3 : 0;
        unsigned int ku0 = *(const unsigned int*)(kb8 + (size_t)s0*128 + l5*4);
        unsigned int ku1 = *(const unsigned int*)(kb8 + (size_t)s1*128 + l5*4);
        unsigned int ku2 = *(const unsigned int*)(kb8 + (size_t)s2*128 + l5*4);
        unsigned int ku3 = *(const unsigned int*)(kb8 + (size_t)s3*128 + l5*4);
        uint2 vv0 = *(const uint2*)(vb + (size_t)s0*128 + l5*4);
        uint2 vv1 = *(const uint2*)(vb + (size_t)s1*128 + l5*4);
        uint2 vv2 = *(const uint2*)(vb + (size_t)s2*128 + l5*4);
        uint2 vv3 = *(const uint2*)(vb + (size_t)s3*128 + l5*4);
        float ka, kb_, kc, kd;
        fp8_to_f4(ku0, ka, kb_, kc, kd);
        float p0 = q0*ka + q1*kb_ + q2*kc + q3*kd;
        fp8_to_f4(ku1, ka, kb_, kc, kd);
        float p1 = q0*ka + q1*kb_ + q2*kc + q3*kd;
        fp8_to_f4(ku2, ka, kb_, kc, kd);
        float p2 = q0*ka + q1*kb_ + q2*kc + q3*kd;
        fp8_to_f4(ku3, ka, kb_, kc, kd);
        float p3 = q0*ka + q1*kb_ + q2*kc + q3*kd;
        p0 += __shfl_xor(p0, 1); p1 += __shfl_xor(p1, 1); p2 += __shfl_xor(p2, 1); p3 += __shfl_xor(p3, 1);
        p0 += __shfl_xor(p0, 2); p1 += __shfl_xor(p1, 2); p2 += __shfl_xor(p2, 2); p3 += __shfl_xor(p3, 2);
        p0 += __shfl_xor(p0, 4); p1 += __shfl_xor(p1, 4); p2 += __shfl_xor(p2, 4); p3 += __shfl_xor(p3, 4);
        float w0 = v0 ? __expf(p0 * scale) : 0.f;
        float w1 = v1 ? __expf(p1 * scale) : 0.f;
        float w2 = v2 ? __expf(p2 * scale) : 0.f;
        float w3 = v3 ? __expf(p3 * scale) : 0.f;
        den += w0 + w1 + w2 + w3;
        a0 += w0*bflo(vv0.x) + w1*bflo(vv1.x) + w2*bflo(vv2.x) + w3*bflo(vv3.x);
        a1 += w0*bfhi(vv0.x) + w1*bfhi(vv1.x) + w2*bfhi(vv2.x) + w3*bfhi(vv3.x);
        a2 += w0*bflo(vv0.y) + w1*bflo(vv1.y) + w2*bflo(vv2.y) + w3*bflo(vv3.y);
        a3 += w0*bfhi(vv0.y) + w1*bfhi(vv1.y) + w2*bfhi(vv2.y) + w3*bfhi(vv3.y);
    }
    // tail: deg > 64 (rare). Half-uniform trip counts; shuffles stay in-half.
    for (int e = 64 + half; e < deg; e += 2){
        int s = csr[e0 + e];
        unsigned int ku = *(const unsigned int*)(kb8 + (size_t)s*128 + l5*4);
        uint2 vv = *(const uint2*)(vb + (size_t)s*128 + l5*4);
        float ka, kb_, kc, kd;
        fp8_to_f4(ku, ka, kb_, kc, kd);
        float p = q0*ka + q1*kb_ + q2*kc + q3*kd;
        p += __shfl_xor(p, 1);
        p += __shfl_xor(p, 2);
        p += __shfl_xor(p, 4);
        float wg = __expf(p * scale);
        den += wg;
        a0 += wg*bflo(vv.x); a1 += wg*bfhi(vv.x);
        a2 += wg*bflo(vv.y); a3 += wg*bfhi(vv.y);
    }
    den += __shfl_xor(den, 32);
    a0 += __shfl_xor(a0, 32); a1 += __shfl_xor(a1, 32);
    a2 += __shfl_xor(a2, 32); a3 += __shfl_xor(a3, 32);
    if (half == 0){
        float inv = (den > 0.f) ? 1.f/den : 0.f;
        float4 o;
        o.x = bflo(sbv.x) + a0*inv;
        o.y = bfhi(sbv.x) + a1*inv;
        o.z = bflo(sbv.y) + a2*inv;
        o.w = bfhi(sbv.y) + a3*inv;
        *(float4*)(h2 + (size_t)n*128 + l5*4) = o;
    }
}

// ---------------------------------------------------------------------------
// SAGE mean aggregation: CSR prefetch, 4 edges/half, fp8 gathers (4 B/lane)
// ---------------------------------------------------------------------------
__global__ __launch_bounds__(256) void sage_agg(const uchar_t* __restrict__ x28,
                                                const int* __restrict__ rs,
                                                const int* __restrict__ csr,
                                                ushort_t* __restrict__ nmeanb){
    int w = threadIdx.x >> 6, lane = threadIdx.x & 63;
    int n = blockIdx.x*4 + w;
    if (n >= NN) return;
    int half = lane >> 5, l5 = lane & 31;
    int e0 = rs[n*8], e1 = rs[n*8 + 8];
    int deg = e1 - e0;
    int idx = 0;
    if (lane < deg) idx = csr[e0 + lane];
    int dcap = min(deg, 64);
    int nt = (dcap + 7) >> 3;
    float a0 = 0.f, a1 = 0.f, a2 = 0.f, a3 = 0.f;
    for (int t = 0; t < nt; ++t){
        int i2 = t*8 + half*4;
        int j0 = i2, j1 = i2+1, j2 = i2+2, j3 = i2+3;
        bool v0 = j0 < dcap, v1 = j1 < dcap, v2 = j2 < dcap, v3 = j3 < dcap;
        int s0 = __shfl(idx, j0 & 63); s0 = v0 ? s0 : 0;
        int s1 = __shfl(idx, j1 & 63); s1 = v1 ? s1 : 0;
        int s2 = __shfl(idx, j2 & 63); s2 = v2 ? s2 : 0;
        int s3 = __shfl(idx, j3 & 63); s3 = v3 ? s3 : 0;
        unsigned int u0 = *(const unsigned int*)(x28 + (size_t)s0*128 + l5*4);
        unsigned int u1 = *(const unsigned int*)(x28 + (size_t)s1*128 + l5*4);
        unsigned int u2 = *(const unsigned int*)(x28 + (size_t)s2*128 + l5*4);
        unsigned int u3 = *(const unsigned int*)(x28 + (size_t)s3*128 + l5*4);
        float fa, fb, fc, fd;
        if (v0){ fp8_to_f4(u0, fa, fb, fc, fd); a0 += fa; a1 += fb; a2 += fc; a3 += fd; }
        if (v1){ fp8_to_f4(u1, fa, fb, fc, fd); a0 += fa; a1 += fb; a2 += fc; a3 += fd; }
        if (v2){ fp8_to_f4(u2, fa, fb, fc, fd); a0 += fa; a1 += fb; a2 += fc; a3 += fd; }
        if (v3){ fp8_to_f4(u3, fa, fb, fc, fd); a0 += fa; a1 += fb; a2 += fc; a3 += fd; }
    }
    for (int e = 64 + half; e < deg; e += 2){
        int s = csr[e0 + e];
        unsigned int u = *(const unsigned int*)(x28 + (size_t)s*128 + l5*4);
        float fa, fb, fc, fd;
        fp8_to_f4(u, fa, fb, fc, fd);
        a0 += fa; a1 += fb; a2 += fc; a3 += fd;
    }
    a0 += __shfl_xor(a0, 32); a1 += __shfl_xor(a1, 32);
    a2 += __shfl_xor(a2, 32); a3 += __shfl_xor(a3, 32);
    if (half == 0){
        float inv = 1.f / fmaxf((float)deg, 1.f);
        ushort4 o;
        o.x = f2bf(a0*inv); o.y = f2bf(a1*inv); o.z = f2bf(a2*inv); o.w = f2bf(a3*inv);
        *(ushort4*)(nmeanb + (size_t)n*128 + l5*4) = o;
    }
}

// ---------------------------------------------------------------------------
extern "C" void kernel_launch(void* const* d_in, const int* in_sizes, int n_in,
                              void* d_out, int out_size, void* d_ws, size_t ws_size,
                              hipStream_t stream){
    const float* nf      = (const float*)d_in[0];
    const int*   ei      = (const int*)d_in[2];
    const int*   et      = (const int*)d_in[3];
    const float* rgcn_w  = (const float*)d_in[4];
    const float* root    = (const float*)d_in[5];
    const float* rbias   = (const float*)d_in[6];
    const float* bn1g    = (const float*)d_in[7];
    const float* bn1b    = (const float*)d_in[8];
    const float* wq      = (const float*)d_in[9];
    const float* bq      = (const float*)d_in[10];
    const float* wk      = (const float*)d_in[11];
    const float* bk      = (const float*)d_in[12];
    const float* wv      = (const float*)d_in[13];
    const float* bv      = (const float*)d_in[14];
    const float* wsk     = (const float*)d_in[15];
    const float* bsk     = (const float*)d_in[16];
    const float* bn2g    = (const float*)d_in[17];
    const float* bn2b    = (const float*)d_in[18];
    const float* wl      = (const float*)d_in[19];
    const float* bl      = (const float*)d_in[20];
    const float* wr      = (const float*)d_in[21];
    const float* bn3g    = (const float*)d_in[22];
    const float* bn3b    = (const float*)d_in[23];
    float* out = (float*)d_out;

    // ---- workspace carve (256B aligned) ----
    char* base = (char*)d_ws;
    size_t off = 0;
    auto take = [&](size_t bytes) -> char* {
        char* p = base + off;
        off += (bytes + 255) & ~(size_t)255;
        return p;
    };
    int*      deg    = (int*)take((size_t)NR*4);
    int*      rs     = (int*)take((size_t)(NR+1)*4);
    int*      tmp    = (int*)take((size_t)NR*4);
    int*      bsum   = (int*)take(1024*4);
    int*      cursor = (int*)take((size_t)NR*4);
    int*      csr    = (int*)take((size_t)NE*4);
    float*    bns    = (float*)take(1024*4);
    char*     zend   = base + off;                     // zero [deg, zend) in one memset
    ushort_t* Wcat   = (ushort_t*)take(64*576*2);
    ushort_t* Wt2    = (ushort_t*)take(512*64*2);
    float*    bcat   = (float*)take(512*4);
    ushort_t* Wsage  = (ushort_t*)take(32*256*2);
    ushort_t* xb     = (ushort_t*)take((size_t)NN*64*2);
    uchar_t*  xb8    = (uchar_t*)take((size_t)NN*64);       // fp8 gather copy (3.2 MB)
    float*    h1pre  = (float*)take((size_t)NN*64*4);
    float*    h2     = (float*)take((size_t)NN*128*4);
    float*    x2r    = (float*)take((size_t)NN*32*4);
    ushort_t* sb     = (ushort_t*)take((size_t)NN*128*2);   // bf16 skip (12.8 MB)
    char*     bigA   = take((size_t)NN*512*2);              // 51.2 MB multi-use
    if (off > ws_size) return;

    // bigA aliases (byte offsets); lifetimes verified stage-by-stage:
    ushort_t* qb     = (ushort_t*)(bigA + (size_t)NN*128);       // gemm_qkvs -> attn (12.8 MB)
    ushort_t* vb     = (ushort_t*)(bigA + (size_t)NN*384);       // gemm_qkvs -> attn (12.8 MB)
    uchar_t*  kb8    = (uchar_t*)(bigA + (size_t)NN*640);        // gemm_qkvs -> attn (6.4 MB)
    ushort_t* x2b    = (ushort_t*)bigA;                          // bn_apply2 -> sage_gemm (12.8 MB)
    uchar_t*  x28    = (uchar_t*)(bigA + (size_t)NN*256);        // bn_apply2 -> sage_agg (6.4 MB)
    ushort_t* nmeanb = (ushort_t*)(bigA + (size_t)NN*512);       // sage_agg -> sage_gemm (12.8 MB)
    float*    h3     = (float*)(bigA + (size_t)NN*768);          // sage_gemm -> bn3 (6.4 MB)

    hipMemsetAsync(deg, 0, (size_t)(zend - (char*)deg), stream); // deg+cursor+bns (rest harmless)

    // ---- CSR build (relation-bucketed) + weight prep ----
    const int PREP_N = NN*16 + 64*576 + 512*64 + 512 + 32*256;
    k_prep <<<(PREP_N+255)/256, 256, 0, stream>>>(nf, rgcn_w, root, wq, wk, wv, wsk,
                                                  bq, bk, bv, bsk, wl, wr,
                                                  xb, xb8, Wcat, Wt2, bcat, Wsage);
    k_deg  <<<(NE+255)/256, 256, 0, stream>>>(ei, et, deg);
    k_scan1<<<NB2, SCAN_BS, 0, stream>>>(deg, tmp, bsum);
    k_scan2<<<1, 1024, 0, stream>>>(bsum);
    k_scan3<<<(NR+255)/256, 256, 0, stream>>>(tmp, bsum, rs);
    k_fill <<<(NE+255)/256, 256, 0, stream>>>(ei, et, rs, cursor, csr);

    const int NB4 = (NN + 3) / 4;
    const int NBG = (NN + 63) / 64;

    // ---- stage 1: RGCN (fused agg + MFMA) ----
    rgcn_fused<<<NN/16, 256, 0, stream>>>(xb, xb8, rs, csr, Wcat, rbias, h1pre);
    bn_stats<64><<<256, 256, 0, stream>>>(h1pre, 64, bns + 0, bns + 64);
    bn1_finalize<<<1, 64, 0, stream>>>(bns + 0, bns + 64, bn1g, bn1b, bns + 448, bns + 512);

    // ---- stage 2: TransformerConv (bn1 fused into gemm_qkvs prologue) ----
    gemm_qkvs<<<dim3(NBG, 2), 256, 0, stream>>>(h1pre, nf, bns + 448, bns + 512,
                                                Wt2, bcat, qb, kb8, vb, sb);
    attn_kernel<<<NB4, 256, 0, stream>>>(qb, kb8, vb, sb, rs, csr, h2);
    bn_stats<128><<<256, 256, 0, stream>>>(h2, 128, bns + 128, bns + 256);
    bn_apply2<<<(NN*128+255)/256, 256, 0, stream>>>(h2, h1pre, nf,
                                                    bn1g, bn1b, bns + 0, bns + 64,
                                                    bn2g, bn2b, bns + 128, bns + 256,
                                                    x2r, x2b, x28);

    // ---- stage 3: SAGE ----
    sage_agg<<<NB4, 256, 0, stream>>>(x28, rs, csr, nmeanb);
    sage_gemm<<<NBG, 256, 0, stream>>>(x2b, nmeanb, Wsage, bl, h3);
    bn_stats<32><<<256, 256, 0, stream>>>(h3, 32, bns + 384, bns + 416);
    bn_apply3<<<(NN*32+255)/256, 256, 0, stream>>>(h3, x2r, bn3g, bn3b, bns + 384, bns + 416, out);
}

// Round 13
// 406.953 us; speedup vs baseline: 1.1194x; 1.0578x over previous
//
#include <hip/hip_runtime.h>
#include <stdint.h>

#define NN 50000
#define NE 800000
#define NR (NN*8)            // (node, relation) segments
#define SCAN_BS 512
#define NB2 782              // ceil(NR/512)
#define INV_N (1.0f/50000.0f)
#define BN_EPS 1e-5f

typedef unsigned short ushort_t;
typedef unsigned char uchar_t;
typedef short bf16x8 __attribute__((ext_vector_type(8)));   // 8 bf16 (4 VGPRs)
typedef float f32x4 __attribute__((ext_vector_type(4)));
typedef float f32x2 __attribute__((ext_vector_type(2)));

__device__ __forceinline__ ushort_t f2bf(float f){
    unsigned int u = __float_as_uint(f);
    u += 0x7FFFu + ((u >> 16) & 1u);      // RNE
    return (ushort_t)(u >> 16);
}
__device__ __forceinline__ float bf2f(ushort_t h){ return __uint_as_float(((unsigned int)h) << 16); }
__device__ __forceinline__ float bflo(unsigned int u){ return __uint_as_float(u << 16); }
__device__ __forceinline__ float bfhi(unsigned int u){ return __uint_as_float(u & 0xFFFF0000u); }

// fp8 e4m3 (OCP) helpers via HW converters
__device__ __forceinline__ unsigned int f4_to_fp8(float a, float b, float c, float d){
    int v = __builtin_amdgcn_cvt_pk_fp8_f32(a, b, 0, false);
    v = __builtin_amdgcn_cvt_pk_fp8_f32(c, d, v, true);
    return (unsigned int)v;
}
__device__ __forceinline__ void fp8_to_f4(unsigned int u, float& a, float& b, float& c, float& d){
    f32x2 lo = __builtin_amdgcn_cvt_pk_f32_fp8(u, false);
    f32x2 hi = __builtin_amdgcn_cvt_pk_f32_fp8(u, true);
    a = lo.x; b = lo.y; c = hi.x; d = hi.y;
}

// ---------------------------------------------------------------------------
// CSR build over (dst, relation) segments.
// R13: k_deg captures atomic rank per edge -> k_fill is atomic-free.
// ---------------------------------------------------------------------------
__global__ void k_deg(const int* __restrict__ ei, const int* __restrict__ et,
                      int* __restrict__ deg, uint2* __restrict__ sr){
    int e = blockIdx.x*256 + threadIdx.x;
    if (e < NE){
        int seg = ei[NE + e]*8 + et[e];
        int rank = atomicAdd(&deg[seg], 1);
        uint2 o; o.x = (unsigned)seg; o.y = (unsigned)rank;
        sr[e] = o;
    }
}

__global__ void k_scan1(const int* __restrict__ deg, int* __restrict__ tmp, int* __restrict__ bsum){
    __shared__ int s[SCAN_BS];
    int t = threadIdx.x;
    int i = blockIdx.x*SCAN_BS + t;
    s[t] = (i < NR) ? deg[i] : 0;
    __syncthreads();
    for (int off = 1; off < SCAN_BS; off <<= 1){
        int add = (t >= off) ? s[t-off] : 0;
        __syncthreads();
        s[t] += add;
        __syncthreads();
    }
    if (i < NR) tmp[i] = s[t];
    if (t == SCAN_BS-1) bsum[blockIdx.x] = s[t];
}

__global__ void k_scan2(int* __restrict__ bsum){
    __shared__ int s[NB2];
    int t = threadIdx.x;
    if (t < NB2) s[t] = bsum[t];
    __syncthreads();
    if (t == 0){
        int acc = 0;
        for (int i = 0; i < NB2; ++i){ acc += s[i]; s[i] = acc; }
    }
    __syncthreads();
    if (t < NB2) bsum[t] = s[t];
}

__global__ void k_scan3(const int* __restrict__ tmp, const int* __restrict__ bsum, int* __restrict__ rs){
    int i = blockIdx.x*256 + threadIdx.x;
    if (i < NR){
        int b = i >> 9;
        int off = (b > 0) ? bsum[b-1] : 0;
        rs[i+1] = tmp[i] + off;
        if (i == 0) rs[0] = 0;
    }
}

// atomic-free: pos = rs[seg] + rank (deterministic, race-free)
__global__ void k_fill(const int* __restrict__ ei, const uint2* __restrict__ sr,
                       const int* __restrict__ rs, int* __restrict__ csr){
    int e = blockIdx.x*256 + threadIdx.x;
    if (e < NE){
        uint2 s = sr[e];
        csr[rs[s.x] + (int)s.y] = ei[e];
    }
}

// ---------------------------------------------------------------------------
// Prep: cast nf->bf16 (xb) + fp8 (xb8), bf16 weight tables, concat biases
// ---------------------------------------------------------------------------
__global__ void k_prep(const float* __restrict__ nf,
                       const float* __restrict__ rgcn_w, const float* __restrict__ root,
                       const float* __restrict__ wq, const float* __restrict__ wk,
                       const float* __restrict__ wv, const float* __restrict__ wsk,
                       const float* __restrict__ bq, const float* __restrict__ bk,
                       const float* __restrict__ bv, const float* __restrict__ bsk,
                       const float* __restrict__ wl, const float* __restrict__ wr,
                       ushort_t* __restrict__ xb, uchar_t* __restrict__ xb8,
                       ushort_t* __restrict__ Wcat,
                       ushort_t* __restrict__ Wt2, float* __restrict__ bcat,
                       ushort_t* __restrict__ Wsage){
    int i = blockIdx.x*256 + threadIdx.x;
    const int NXB = NN*16;
    if (i < NXB){
        float4 v = ((const float4*)nf)[i];
        ushort4 h;
        h.x = f2bf(v.x); h.y = f2bf(v.y); h.z = f2bf(v.z); h.w = f2bf(v.w);
        ((ushort4*)xb)[i] = h;
        ((unsigned int*)xb8)[i] = f4_to_fp8(v.x, v.y, v.z, v.w);
        return;
    }
    int j = i - NXB;
    if (j < 64*576){
        int h = j / 576, k = j - h*576;
        float v = (k < 512) ? rgcn_w[(size_t)k*64 + h] : root[(size_t)(k-512)*64 + h];
        Wcat[j] = f2bf(v);
    } else if (j < 64*576 + 512*64){
        int jj = j - 64*576;
        int c = jj >> 6, k = jj & 63;
        int mt = c >> 7, cc = c & 127;
        const float* W = (mt==0)?wq:(mt==1)?wk:(mt==2)?wv:wsk;
        Wt2[jj] = f2bf(W[(size_t)k*128 + cc]);
    } else if (j < 64*576 + 512*64 + 512){
        int c = j - (64*576 + 512*64);
        int mt = c >> 7, cc = c & 127;
        const float* B = (mt==0)?bq:(mt==1)?bk:(mt==2)?bv:bsk;
        bcat[c] = B[cc];
    } else if (j < 64*576 + 512*64 + 512 + 32*256){
        int jj = j - (64*576 + 512*64 + 512);
        int c = jj >> 8, k = jj & 255;
        float v = (k < 128) ? wr[(size_t)k*32 + c] : wl[(size_t)(k-128)*32 + c];
        Wsage[jj] = f2bf(v);
    }
}

// ---------------------------------------------------------------------------
// FUSED RGCN. Phase 1: quad owns relations {quad,quad+4}; gather loop
// unrolled i+=4 (8 loads in flight/lane); node j+1's rs row + csr chunk
// prefetched before node j's loop. Phase 2: 16x64 MFMA, K=576.
// ---------------------------------------------------------------------------
__global__ __launch_bounds__(256) void rgcn_fused(const ushort_t* __restrict__ xb,
                                                  const uchar_t* __restrict__ xb8,
                                                  const int* __restrict__ rs,
                                                  const int* __restrict__ csr,
                                                  const ushort_t* __restrict__ Wcat,
                                                  const float* __restrict__ bias,
                                                  float* __restrict__ h1pre){
    __shared__ ushort_t Ml[16*520];
    int w = threadIdx.x >> 6, lane = threadIdx.x & 63;
    int quad = lane >> 4, l4 = lane & 15;
    int row0 = blockIdx.x * 16;                 // 3125*16 == 50000 exactly
    int n0 = row0 + w*4;
    int rsel = (lane < 9 ? lane : 8);
    int rb = rs[n0*8 + rsel];
    int eb0 = __shfl(rb, 0);
    int dg0 = __shfl(rb, 8) - eb0;
    int idx = (lane < dg0) ? csr[eb0 + lane] : 0;
    for (int j = 0; j < 4; ++j){
        int lrow = (w*4 + j)*520;
        int ebase = __shfl(rb, 0);
        int enext = __shfl(rb, 8);
        int rb_next = 0, idxn = 0;
        if (j < 3){
            rb_next = rs[(n0 + j + 1)*8 + rsel];
            idxn = csr[min(enext + lane, NE - 1)];   // addr independent of rb_next
        }
        int e0a = __shfl(rb, quad),     e1a = __shfl(rb, quad + 1);
        int e0b = __shfl(rb, quad + 4), e1b = __shfl(rb, quad + 5);
        int oa = e0a - ebase, la = e1a - e0a;
        int ob = e0b - ebase, lb = e1b - e0b;
        int ml = max(la, lb);
        ml = max(ml, __shfl_xor(ml, 16));
        ml = max(ml, __shfl_xor(ml, 32));
        float aa0=0.f, aa1=0.f, aa2=0.f, aa3=0.f;
        float ab0=0.f, ab1=0.f, ab2=0.f, ab3=0.f;
        for (int i = 0; i < ml; i += 4){
            int sA[4], sB[4];
            bool vA[4], vB[4];
#pragma unroll
            for (int u = 0; u < 4; ++u){
                int jA = oa + i + u, jB = ob + i + u;
                vA[u] = (i + u) < la;
                vB[u] = (i + u) < lb;
                int tA = __shfl(idx, jA & 63);
                int tB = __shfl(idx, jB & 63);
                if (jA >= 64 && vA[u]) tA = csr[ebase + jA];   // rare (deg>64)
                if (jB >= 64 && vB[u]) tB = csr[ebase + jB];
                sA[u] = vA[u] ? tA : 0;
                sB[u] = vB[u] ? tB : 0;
            }
            unsigned int uA[4], uB[4];
#pragma unroll
            for (int u = 0; u < 4; ++u){
                uA[u] = *(const unsigned int*)(xb8 + (size_t)sA[u]*64 + l4*4);
                uB[u] = *(const unsigned int*)(xb8 + (size_t)sB[u]*64 + l4*4);
            }
#pragma unroll
            for (int u = 0; u < 4; ++u){
                float f0,f1,f2,f3;
                fp8_to_f4(uA[u],f0,f1,f2,f3);
                if (vA[u]){ aa0+=f0; aa1+=f1; aa2+=f2; aa3+=f3; }
                fp8_to_f4(uB[u],f0,f1,f2,f3);
                if (vB[u]){ ab0+=f0; ab1+=f1; ab2+=f2; ab3+=f3; }
            }
        }
        float inva = 1.f / fmaxf((float)la, 1.f);
        float invb = 1.f / fmaxf((float)lb, 1.f);
        ushort4 oA, oB;
        oA.x = f2bf(aa0*inva); oA.y = f2bf(aa1*inva); oA.z = f2bf(aa2*inva); oA.w = f2bf(aa3*inva);
        oB.x = f2bf(ab0*invb); oB.y = f2bf(ab1*invb); oB.z = f2bf(ab2*invb); oB.w = f2bf(ab3*invb);
        *(ushort4*)&Ml[lrow + quad*64 + l4*4] = oA;
        *(ushort4*)&Ml[lrow + (quad + 4)*64 + l4*4] = oB;
        if (j < 3){
            rb = rb_next;
            int ebn = __shfl(rb, 0);
            int dgn = __shfl(rb, 8) - ebn;
            idx = (lane < dgn) ? idxn : 0;
        }
    }
    __syncthreads();
    int m = l4;
    f32x4 acc = {};
#pragma unroll
    for (int kt = 0; kt < 18; ++kt){
        int kk = kt*32 + quad*8;
        bf16x8 a;
        if (kt < 16) a = *(const bf16x8*)&Ml[m*520 + kk];
        else         a = *(const bf16x8*)(xb + (size_t)(row0 + m)*64 + (kk - 512));
        bf16x8 b = *(const bf16x8*)(Wcat + (size_t)(w*16 + m)*576 + kk);
        acc = __builtin_amdgcn_mfma_f32_16x16x32_bf16(a, b, acc, 0, 0, 0);
    }
    int col = w*16 + m;
    float bz = bias[col];
#pragma unroll
    for (int i = 0; i < 4; ++i){
        int rr = row0 + quad*4 + i;
        h1pre[(size_t)rr*64 + col] = acc[i] + bz;
    }
}

// bn1 finalize: fold to scale/shift: A = rsv*g, C = b - m*A  (one wave)
__global__ void bn1_finalize(const float* __restrict__ sums, const float* __restrict__ sumsq,
                             const float* __restrict__ g1, const float* __restrict__ b1,
                             float* __restrict__ A1, float* __restrict__ C1){
    int c = threadIdx.x;
    if (c < 64){
        float m = sums[c] * INV_N;
        float v = sumsq[c] * INV_N - m*m;
        float rsv = rsqrtf(fmaxf(v, 0.f) + BN_EPS);
        float A = rsv * g1[c];
        A1[c] = A;
        C1[c] = b1[c] - m * A;
    }
}

// ---------------------------------------------------------------------------
// MFMA GEMM 2: Wt2 col-group tile staged in LDS (kills L1 B re-reads);
// bn1 scale/shift prologue; blockIdx.y = col-group; per-wave pl epilogue.
// ---------------------------------------------------------------------------
#define QS 132   // pl row stride (ushorts)
#define BS 68    // Bs row stride (ushorts): 2-way bank alias (free, m136)
__global__ __launch_bounds__(256) void gemm_qkvs(const float* __restrict__ h1pre,
                                                 const float* __restrict__ nf,
                                                 const float* __restrict__ A1, const float* __restrict__ C1,
                                                 const ushort_t* __restrict__ Wt2,
                                                 const float* __restrict__ bcat,
                                                 ushort_t* __restrict__ qb,
                                                 uchar_t* __restrict__ kb8,
                                                 ushort_t* __restrict__ vb,
                                                 ushort_t* __restrict__ sb){
    __shared__ ushort_t Bs[256*BS];
    __shared__ ushort_t pl[4][16*QS];
    int w = threadIdx.x >> 6, lane = threadIdx.x & 63;
    int m = lane & 15, quad = lane >> 4;
    int r0 = blockIdx.x*64 + w*16;
    int cg = blockIdx.y;
    int row = r0 + m;
    // ---- stage Wt2 col-group tile: 256 rows x 64 ush = 2048 uint4 ----
    {
        int t = threadIdx.x;
        const ushort_t* wsrc = Wt2 + (size_t)cg*256*64;
#pragma unroll
        for (int u0 = 0; u0 < 8; ++u0){
            int u = u0*256 + t;
            int r = u >> 3, c8 = (u & 7)*8;
            *(uint4*)&Bs[r*BS + c8] = *(const uint4*)(wsrc + u*8);
        }
    }
    // ---- prologue: x1 fragments = bf16(leaky(h*A+C) + nf) ----
    bf16x8 afrag[2];
#pragma unroll
    for (int kt = 0; kt < 2; ++kt){
        int db = kt*32 + quad*8;
        bf16x8 f = (bf16x8){0,0,0,0,0,0,0,0};
        if (row < NN){
            float4 h0 = *(const float4*)(h1pre + (size_t)row*64 + db);
            float4 h1 = *(const float4*)(h1pre + (size_t)row*64 + db + 4);
            float4 n0 = *(const float4*)(nf + (size_t)row*64 + db);
            float4 n1 = *(const float4*)(nf + (size_t)row*64 + db + 4);
            float4 a0 = *(const float4*)(A1 + db);
            float4 a1 = *(const float4*)(A1 + db + 4);
            float4 c0 = *(const float4*)(C1 + db);
            float4 c1 = *(const float4*)(C1 + db + 4);
            float hh[8] = {h0.x,h0.y,h0.z,h0.w,h1.x,h1.y,h1.z,h1.w};
            float nn[8] = {n0.x,n0.y,n0.z,n0.w,n1.x,n1.y,n1.z,n1.w};
            float AA[8] = {a0.x,a0.y,a0.z,a0.w,a1.x,a1.y,a1.z,a1.w};
            float CC[8] = {c0.x,c0.y,c0.z,c0.w,c1.x,c1.y,c1.z,c1.w};
#pragma unroll
            for (int e = 0; e < 8; ++e){
                float y = fmaf(hh[e], AA[e], CC[e]);
                y = (y >= 0.f) ? y : 0.01f*y;
                f[e] = (short)f2bf(y + nn[e]);
            }
        }
        afrag[kt] = f;
    }
    __syncthreads();
    f32x4 acc[16] = {};
#pragma unroll
    for (int kt = 0; kt < 2; ++kt){
        int kk = kt*32 + quad*8;
#pragma unroll
        for (int ct = 0; ct < 16; ++ct){
            bf16x8 b = *(const bf16x8*)&Bs[(size_t)(ct*16 + m)*BS + kk];
            acc[ct] = __builtin_amdgcn_mfma_f32_16x16x32_bf16(afrag[kt], b, acc[ct], 0, 0, 0);
        }
    }
    // ---- half 0 (ct 0..7): cg0 -> q, cg1 -> v ----
#pragma unroll
    for (int ct = 0; ct < 8; ++ct){
        int g = cg*256 + ct*16 + m;
        float bz = bcat[g];
        int cc = g & 127;
#pragma unroll
        for (int i = 0; i < 4; ++i)
            pl[w][(quad*4 + i)*QS + cc] = f2bf(acc[ct][i] + bz);
    }
    if (cg == 0){
#pragma unroll
        for (int t = 0; t < 4; ++t){
            int u = t*64 + lane;
            int r = u >> 4, c = (u & 15)*8;
            int gr = r0 + r;
            if (gr < NN) *(uint4*)(qb + (size_t)gr*128 + c) = *(const uint4*)&pl[w][r*QS + c];
        }
    } else {
#pragma unroll
        for (int t = 0; t < 4; ++t){
            int u = t*64 + lane;
            int r = u >> 4, c = (u & 15)*8;
            int gr = r0 + r;
            if (gr < NN) *(uint4*)(vb + (size_t)gr*128 + c) = *(const uint4*)&pl[w][r*QS + c];
        }
    }
    // ---- half 1 (ct 8..15): cg0 -> k (fp8), cg1 -> skip ----
#pragma unroll
    for (int ct = 8; ct < 16; ++ct){
        int g = cg*256 + ct*16 + m;
        float bz = bcat[g];
        int cc = g & 127;
#pragma unroll
        for (int i = 0; i < 4; ++i)
            pl[w][(quad*4 + i)*QS + cc] = f2bf(acc[ct][i] + bz);
    }
    if (cg == 0){
#pragma unroll
        for (int t = 0; t < 4; ++t){
            int u = t*64 + lane;
            int r = u >> 4, c = (u & 15)*8;
            int gr = r0 + r;
            if (gr < NN){
                uint4 kk4 = *(const uint4*)&pl[w][r*QS + c];
                uint2 o;
                o.x = f4_to_fp8(bflo(kk4.x), bfhi(kk4.x), bflo(kk4.y), bfhi(kk4.y));
                o.y = f4_to_fp8(bflo(kk4.z), bfhi(kk4.z), bflo(kk4.w), bfhi(kk4.w));
                *(uint2*)(kb8 + (size_t)gr*128 + c) = o;
            }
        }
    } else {
#pragma unroll
        for (int t = 0; t < 4; ++t){
            int u = t*64 + lane;
            int r = u >> 4, c = (u & 15)*8;
            int gr = r0 + r;
            if (gr < NN) *(uint4*)(sb + (size_t)gr*128 + c) = *(const uint4*)&pl[w][r*QS + c];
        }
    }
}

// ---------------------------------------------------------------------------
// MFMA GEMM 3: h3 = [x2b | nmeanb](50000x256) @ Wsage^T + bl   (32 cols)
// ---------------------------------------------------------------------------
__global__ __launch_bounds__(256) void sage_gemm(const ushort_t* __restrict__ x2b,
                                                 const ushort_t* __restrict__ nmeanb,
                                                 const ushort_t* __restrict__ Wsage,
                                                 const float* __restrict__ bl,
                                                 float* __restrict__ h3){
    int wv = threadIdx.x >> 6, lane = threadIdx.x & 63;
    int r0 = blockIdx.x*64 + wv*16;
    int m = lane & 15, quad = lane >> 4;
    int row = r0 + m;
    f32x4 acc[2] = {};
#pragma unroll
    for (int kt = 0; kt < 8; ++kt){
        int kk = kt*32 + quad*8;
        bf16x8 a;
        if (row < NN){
            const ushort_t* ap = (kt < 4) ? (x2b + (size_t)row*128 + kk)
                                          : (nmeanb + (size_t)row*128 + (kk - 128));
            a = *(const bf16x8*)ap;
        } else {
            a = (bf16x8){0,0,0,0,0,0,0,0};
        }
#pragma unroll
        for (int ct = 0; ct < 2; ++ct){
            bf16x8 b = *(const bf16x8*)(Wsage + (size_t)(ct*16 + m)*256 + kk);
            acc[ct] = __builtin_amdgcn_mfma_f32_16x16x32_bf16(a, b, acc[ct], 0, 0, 0);
        }
    }
#pragma unroll
    for (int ct = 0; ct < 2; ++ct){
        int col = ct*16 + m;
        float bz = bl[col];
#pragma unroll
        for (int i = 0; i < 4; ++i){
            int rr = r0 + quad*4 + i;
            if (rr < NN) h3[(size_t)rr*32 + col] = acc[ct][i] + bz;
        }
    }
}

// ---------------------------------------------------------------------------
// BatchNorm stats (dense layouts)
// ---------------------------------------------------------------------------
template<int C>
__global__ __launch_bounds__(256) void bn_stats(const float* __restrict__ X, int ld,
                                                float* __restrict__ sums, float* __restrict__ sumsq){
    __shared__ float s1[256], s2[256];
    int t = threadIdx.x;
    int c = t & (C-1);
    const int rpb = 256 / C;
    int r = blockIdx.x * rpb + (t / C);
    int rstride = gridDim.x * rpb;
    float a = 0.f, b = 0.f;
    for (; r < NN; r += rstride){
        float v = X[(size_t)r*ld + c];
        a += v; b += v*v;
    }
    s1[t] = a; s2[t] = b;
    __syncthreads();
    for (int off = 128; off >= C; off >>= 1){
        if (t < off){ s1[t] += s1[t+off]; s2[t] += s2[t+off]; }
        __syncthreads();
    }
    if (t < C){ atomicAdd(&sums[t], s1[t]); atomicAdd(&sumsq[t], s2[t]); }
}

__device__ __forceinline__ float bn_leaky(float z, float m, float rsv, float g, float b){
    float y = (z - m) * rsv * g + b;
    return y >= 0.f ? y : 0.01f * y;
}

// x2 = leaky(bn2(h2)) + (c<64 ? x1 : 0); -> bf16 x2b, fp8 x28, cols<32 fp32 x2r
__global__ void bn_apply2(const float* __restrict__ h2, const float* __restrict__ h1pre,
                          const float* __restrict__ nf,
                          const float* __restrict__ g1, const float* __restrict__ b1,
                          const float* __restrict__ s1, const float* __restrict__ q1,
                          const float* __restrict__ g2, const float* __restrict__ b2,
                          const float* __restrict__ s2, const float* __restrict__ q2,
                          float* __restrict__ x2r, ushort_t* __restrict__ x2b,
                          uchar_t* __restrict__ x28){
    int i = blockIdx.x*256 + threadIdx.x;
    if (i >= NN*128) return;
    int n = i >> 7, c = i & 127;
    float m2 = s2[c] * INV_N;
    float v2 = q2[c] * INV_N - m2*m2;
    float rsv2 = rsqrtf(fmaxf(v2, 0.f) + BN_EPS);
    float val = bn_leaky(h2[i], m2, rsv2, g2[c], b2[c]);
    if (c < 64){
        float m1 = s1[c] * INV_N;
        float v1 = q1[c] * INV_N - m1*m1;
        float rsv1 = rsqrtf(fmaxf(v1, 0.f) + BN_EPS);
        val += bn_leaky(h1pre[(size_t)n*64 + c], m1, rsv1, g1[c], b1[c]) + nf[(size_t)n*64 + c];
    }
    if (c < 32) x2r[(size_t)n*32 + c] = val;
    x2b[i] = f2bf(val);
    int p = __builtin_amdgcn_cvt_pk_fp8_f32(val, val, 0, false);
    x28[i] = (uchar_t)(p & 0xFF);
}

__global__ void bn_apply3(const float* __restrict__ h3, const float* __restrict__ x2r,
                          const float* __restrict__ g, const float* __restrict__ b,
                          const float* __restrict__ sums, const float* __restrict__ sumsq,
                          float* __restrict__ out){
    int i = blockIdx.x*256 + threadIdx.x;
    if (i >= NN*32) return;
    int c = i & 31;
    float m = sums[c] * INV_N;
    float v = sumsq[c] * INV_N - m*m;
    float rsv = rsqrtf(fmaxf(v, 0.f) + BN_EPS);
    out[i] = bn_leaky(h3[i], m, rsv, g[c], b[c]) + x2r[i];
}

// ---------------------------------------------------------------------------
// Attention: wave per dst node, CSR prefetch, 4 edges per half-wave in
// flight. k gathered as fp8 (4 B/lane), v as bf16 (8 B/lane) — 384 B/edge.
// Writes h2 = sb (skip) + attention output for ALL nodes.
// ---------------------------------------------------------------------------
__global__ __launch_bounds__(256) void attn_kernel(const ushort_t* __restrict__ qb,
                                                   const uchar_t* __restrict__ kb8,
                                                   const ushort_t* __restrict__ vb,
                                                   const ushort_t* __restrict__ sb,
                                                   const int* __restrict__ rs,
                                                   const int* __restrict__ csr,
                                                   float* __restrict__ h2){
    int w = threadIdx.x >> 6, lane = threadIdx.x & 63;
    int n = blockIdx.x*4 + w;
    if (n >= NN) return;
    int half = lane >> 5, l5 = lane & 31;
    int e0 = rs[n*8], e1 = rs[n*8 + 8];
    int deg = e1 - e0;
    uint2 qu = *(const uint2*)(qb + (size_t)n*128 + l5*4);
    uint2 sbv = *(const uint2*)(sb + (size_t)n*128 + l5*4);
    float q0 = bflo(qu.x), q1 = bfhi(qu.x), q2 = bflo(qu.y), q3 = bfhi(qu.y);
    const float scale = 0.17677669529663687f;   // 1/sqrt(32)
    int idx = 0;
    if (lane < deg) idx = csr[e0 + lane];
    int dcap = min(deg, 64);
    int nt = (dcap + 7) >> 3;
    float den = 0.f, a0 = 0.f, a1 = 0.f, a2 = 0.f, a3 = 0.f;
    for (int t = 0; t < nt; ++t){
        int i2 = t*8 + half*4;
        int j0 = i2, j1 = i2+1, j2 = i2+2, j3 = i2+3;
        bool v0 = j0 < dcap, v1 = j1 < dcap, v2 = j2 < dcap, v3 = j3 < dcap;
        int s0 = __shfl(idx, j0 & 63); s0 = v0 ? s0 : 0;
        int s1 = __shfl(idx, j1 & 63); s1 = v1 ? s1 : 0;
        int s2 = __shfl(idx, j2 & 63); s2 = v2 ? s2 : 0;
        int s3 = __shfl(idx, j3 & 63); s3 = v3 ? s3 : 0;
        unsigned int ku0 = *(const unsigned int*)(kb8 + (size_t)s0*128 + l5*4);
        unsigned int ku1 = *(const unsigned int*)(kb8 + (size_t)s1*128 + l5*4);
        unsigned int ku2 = *(const unsigned int*)(kb8 + (size_t)s2*128 + l5*4);
        unsigned int ku3 = *(const unsigned int*)(kb8 + (size_t)s3*128 + l5*4);
        uint2 vv0 = *(const uint2*)(vb + (size_t)s0*128 + l5*4);
        uint2 vv1 = *(const uint2*)(vb + (size_t)s1*128 + l5*4);
        uint2 vv2 = *(const uint2*)(vb + (size_t)s2*128 + l5*4);
        uint2 vv3 = *(const uint2*)(vb + (size_t)s3*128 + l5*4);
        float ka, kb_, kc, kd;
        fp8_to_f4(ku0, ka, kb_, kc, kd);
        float p0 = q0*ka + q1*kb_ + q2*kc + q3*kd;
        fp8_to_f4(ku1, ka, kb_, kc, kd);
        float p1 = q0*ka + q1*kb_ + q2*kc + q3*kd;
        fp8_to_f4(ku2, ka, kb_, kc, kd);
        float p2 = q0*ka + q1*kb_ + q2*kc + q3*kd;
        fp8_to_f4(ku3, ka, kb_, kc, kd);
        float p3 = q0*ka + q1*kb_ + q2*kc + q3*kd;
        p0 += __shfl_xor(p0, 1); p1 += __shfl_xor(p1, 1); p2 += __shfl_xor(p2, 1); p3 += __shfl_xor(p3, 1);
        p0 += __shfl_xor(p0, 2); p1 += __shfl_xor(p1, 2); p2 += __shfl_xor(p2, 2); p3 += __shfl_xor(p3, 2);
        p0 += __shfl_xor(p0, 4); p1 += __shfl_xor(p1, 4); p2 += __shfl_xor(p2, 4); p3 += __shfl_xor(p3, 4);
        float w0 = v0 ? __expf(p0 * scale) : 0.f;
        float w1 = v1 ? __expf(p1 * scale) : 0.f;
        float w2 = v2 ? __expf(p2 * scale) : 0.f;
        float w3 = v3 ? __expf(p3 * scale) : 0.f;
        den += w0 + w1 + w2 + w3;
        a0 += w0*bflo(vv0.x) + w1*bflo(vv1.x) + w2*bflo(vv2.x) + w3*bflo(vv3.x);
        a1 += w0*bfhi(vv0.x) + w1*bfhi(vv1.x) + w2*bfhi(vv2.x) + w3*bfhi(vv3.x);
        a2 += w0*bflo(vv0.y) + w1*bflo(vv1.y) + w2*bflo(vv2.y) + w3*bflo(vv3.y);
        a3 += w0*bfhi(vv0.y) + w1*bfhi(vv1.y) + w2*bfhi(vv2.y) + w3*bfhi(vv3.y);
    }
    // tail: deg > 64 (rare). Half-uniform trip counts; shuffles stay in-half.
    for (int e = 64 + half; e < deg; e += 2){
        int s = csr[e0 + e];
        unsigned int ku = *(const unsigned int*)(kb8 + (size_t)s*128 + l5*4);
        uint2 vv = *(const uint2*)(vb + (size_t)s*128 + l5*4);
        float ka, kb_, kc, kd;
        fp8_to_f4(ku, ka, kb_, kc, kd);
        float p = q0*ka + q1*kb_ + q2*kc + q3*kd;
        p += __shfl_xor(p, 1);
        p += __shfl_xor(p, 2);
        p += __shfl_xor(p, 4);
        float wg = __expf(p * scale);
        den += wg;
        a0 += wg*bflo(vv.x); a1 += wg*bfhi(vv.x);
        a2 += wg*bflo(vv.y); a3 += wg*bfhi(vv.y);
    }
    den += __shfl_xor(den, 32);
    a0 += __shfl_xor(a0, 32); a1 += __shfl_xor(a1, 32);
    a2 += __shfl_xor(a2, 32); a3 += __shfl_xor(a3, 32);
    if (half == 0){
        float inv = (den > 0.f) ? 1.f/den : 0.f;
        float4 o;
        o.x = bflo(sbv.x) + a0*inv;
        o.y = bfhi(sbv.x) + a1*inv;
        o.z = bflo(sbv.y) + a2*inv;
        o.w = bfhi(sbv.y) + a3*inv;
        *(float4*)(h2 + (size_t)n*128 + l5*4) = o;
    }
}

// ---------------------------------------------------------------------------
// SAGE mean aggregation: CSR prefetch, 4 edges/half, fp8 gathers (4 B/lane)
// ---------------------------------------------------------------------------
__global__ __launch_bounds__(256) void sage_agg(const uchar_t* __restrict__ x28,
                                                const int* __restrict__ rs,
                                                const int* __restrict__ csr,
                                                ushort_t* __restrict__ nmeanb){
    int w = threadIdx.x >> 6, lane = threadIdx.x & 63;
    int n = blockIdx.x*4 + w;
    if (n >= NN) return;
    int half = lane >> 5, l5 = lane & 31;
    int e0 = rs[n*8], e1 = rs[n*8 + 8];
    int deg = e1 - e0;
    int idx = 0;
    if (lane < deg) idx = csr[e0 + lane];
    int dcap = min(deg, 64);
    int nt = (dcap + 7) >> 3;
    float a0 = 0.f, a1 = 0.f, a2 = 0.f, a3 = 0.f;
    for (int t = 0; t < nt; ++t){
        int i2 = t*8 + half*4;
        int j0 = i2, j1 = i2+1, j2 = i2+2, j3 = i2+3;
        bool v0 = j0 < dcap, v1 = j1 < dcap, v2 = j2 < dcap, v3 = j3 < dcap;
        int s0 = __shfl(idx, j0 & 63); s0 = v0 ? s0 : 0;
        int s1 = __shfl(idx, j1 & 63); s1 = v1 ? s1 : 0;
        int s2 = __shfl(idx, j2 & 63); s2 = v2 ? s2 : 0;
        int s3 = __shfl(idx, j3 & 63); s3 = v3 ? s3 : 0;
        unsigned int u0 = *(const unsigned int*)(x28 + (size_t)s0*128 + l5*4);
        unsigned int u1 = *(const unsigned int*)(x28 + (size_t)s1*128 + l5*4);
        unsigned int u2 = *(const unsigned int*)(x28 + (size_t)s2*128 + l5*4);
        unsigned int u3 = *(const unsigned int*)(x28 + (size_t)s3*128 + l5*4);
        float fa, fb, fc, fd;
        if (v0){ fp8_to_f4(u0, fa, fb, fc, fd); a0 += fa; a1 += fb; a2 += fc; a3 += fd; }
        if (v1){ fp8_to_f4(u1, fa, fb, fc, fd); a0 += fa; a1 += fb; a2 += fc; a3 += fd; }
        if (v2){ fp8_to_f4(u2, fa, fb, fc, fd); a0 += fa; a1 += fb; a2 += fc; a3 += fd; }
        if (v3){ fp8_to_f4(u3, fa, fb, fc, fd); a0 += fa; a1 += fb; a2 += fc; a3 += fd; }
    }
    for (int e = 64 + half; e < deg; e += 2){
        int s = csr[e0 + e];
        unsigned int u = *(const unsigned int*)(x28 + (size_t)s*128 + l5*4);
        float fa, fb, fc, fd;
        fp8_to_f4(u, fa, fb, fc, fd);
        a0 += fa; a1 += fb; a2 += fc; a3 += fd;
    }
    a0 += __shfl_xor(a0, 32); a1 += __shfl_xor(a1, 32);
    a2 += __shfl_xor(a2, 32); a3 += __shfl_xor(a3, 32);
    if (half == 0){
        float inv = 1.f / fmaxf((float)deg, 1.f);
        ushort4 o;
        o.x = f2bf(a0*inv); o.y = f2bf(a1*inv); o.z = f2bf(a2*inv); o.w = f2bf(a3*inv);
        *(ushort4*)(nmeanb + (size_t)n*128 + l5*4) = o;
    }
}

// ---------------------------------------------------------------------------
extern "C" void kernel_launch(void* const* d_in, const int* in_sizes, int n_in,
                              void* d_out, int out_size, void* d_ws, size_t ws_size,
                              hipStream_t stream){
    const float* nf      = (const float*)d_in[0];
    const int*   ei      = (const int*)d_in[2];
    const int*   et      = (const int*)d_in[3];
    const float* rgcn_w  = (const float*)d_in[4];
    const float* root    = (const float*)d_in[5];
    const float* rbias   = (const float*)d_in[6];
    const float* bn1g    = (const float*)d_in[7];
    const float* bn1b    = (const float*)d_in[8];
    const float* wq      = (const float*)d_in[9];
    const float* bq      = (const float*)d_in[10];
    const float* wk      = (const float*)d_in[11];
    const float* bk      = (const float*)d_in[12];
    const float* wv      = (const float*)d_in[13];
    const float* bv      = (const float*)d_in[14];
    const float* wsk     = (const float*)d_in[15];
    const float* bsk     = (const float*)d_in[16];
    const float* bn2g    = (const float*)d_in[17];
    const float* bn2b    = (const float*)d_in[18];
    const float* wl      = (const float*)d_in[19];
    const float* bl      = (const float*)d_in[20];
    const float* wr      = (const float*)d_in[21];
    const float* bn3g    = (const float*)d_in[22];
    const float* bn3b    = (const float*)d_in[23];
    float* out = (float*)d_out;

    // ---- workspace carve (256B aligned) ----
    char* base = (char*)d_ws;
    size_t off = 0;
    auto take = [&](size_t bytes) -> char* {
        char* p = base + off;
        off += (bytes + 255) & ~(size_t)255;
        return p;
    };
    int*      deg    = (int*)take((size_t)NR*4);
    float*    bns    = (float*)take(1024*4);
    char*     zend   = base + off;                     // zero [deg, zend) in one memset
    int*      rs     = (int*)take((size_t)(NR+1)*4);
    int*      tmp    = (int*)take((size_t)NR*4);
    int*      bsum   = (int*)take(1024*4);
    uint2*    sr     = (uint2*)take((size_t)NE*8);          // (seg, rank) per edge (6.4 MB)
    int*      csr    = (int*)take((size_t)NE*4);
    ushort_t* Wcat   = (ushort_t*)take(64*576*2);
    ushort_t* Wt2    = (ushort_t*)take(512*64*2);
    float*    bcat   = (float*)take(512*4);
    ushort_t* Wsage  = (ushort_t*)take(32*256*2);
    ushort_t* xb     = (ushort_t*)take((size_t)NN*64*2);
    uchar_t*  xb8    = (uchar_t*)take((size_t)NN*64);       // fp8 gather copy (3.2 MB)
    float*    h1pre  = (float*)take((size_t)NN*64*4);
    float*    h2     = (float*)take((size_t)NN*128*4);
    float*    x2r    = (float*)take((size_t)NN*32*4);
    ushort_t* sb     = (ushort_t*)take((size_t)NN*128*2);   // bf16 skip (12.8 MB)
    char*     bigA   = take((size_t)NN*512*2);              // 51.2 MB multi-use
    if (off > ws_size) return;

    // bigA aliases (byte offsets); lifetimes verified stage-by-stage:
    ushort_t* qb     = (ushort_t*)(bigA + (size_t)NN*128);       // gemm_qkvs -> attn (12.8 MB)
    ushort_t* vb     = (ushort_t*)(bigA + (size_t)NN*384);       // gemm_qkvs -> attn (12.8 MB)
    uchar_t*  kb8    = (uchar_t*)(bigA + (size_t)NN*640);        // gemm_qkvs -> attn (6.4 MB)
    ushort_t* x2b    = (ushort_t*)bigA;                          // bn_apply2 -> sage_gemm (12.8 MB)
    uchar_t*  x28    = (uchar_t*)(bigA + (size_t)NN*256);        // bn_apply2 -> sage_agg (6.4 MB)
    ushort_t* nmeanb = (ushort_t*)(bigA + (size_t)NN*512);       // sage_agg -> sage_gemm (12.8 MB)
    float*    h3     = (float*)(bigA + (size_t)NN*768);          // sage_gemm -> bn3 (6.4 MB)

    hipMemsetAsync(deg, 0, (size_t)(zend - (char*)deg), stream); // deg + bns

    // ---- CSR build (relation-bucketed, atomic-free fill) + weight prep ----
    const int PREP_N = NN*16 + 64*576 + 512*64 + 512 + 32*256;
    k_prep <<<(PREP_N+255)/256, 256, 0, stream>>>(nf, rgcn_w, root, wq, wk, wv, wsk,
                                                  bq, bk, bv, bsk, wl, wr,
                                                  xb, xb8, Wcat, Wt2, bcat, Wsage);
    k_deg  <<<(NE+255)/256, 256, 0, stream>>>(ei, et, deg, sr);
    k_scan1<<<NB2, SCAN_BS, 0, stream>>>(deg, tmp, bsum);
    k_scan2<<<1, 1024, 0, stream>>>(bsum);
    k_scan3<<<(NR+255)/256, 256, 0, stream>>>(tmp, bsum, rs);
    k_fill <<<(NE+255)/256, 256, 0, stream>>>(ei, sr, rs, csr);

    const int NB4 = (NN + 3) / 4;
    const int NBG = (NN + 63) / 64;

    // ---- stage 1: RGCN (fused agg + MFMA) ----
    rgcn_fused<<<NN/16, 256, 0, stream>>>(xb, xb8, rs, csr, Wcat, rbias, h1pre);
    bn_stats<64><<<256, 256, 0, stream>>>(h1pre, 64, bns + 0, bns + 64);
    bn1_finalize<<<1, 64, 0, stream>>>(bns + 0, bns + 64, bn1g, bn1b, bns + 448, bns + 512);

    // ---- stage 2: TransformerConv (bn1 fused into gemm_qkvs prologue) ----
    gemm_qkvs<<<dim3(NBG, 2), 256, 0, stream>>>(h1pre, nf, bns + 448, bns + 512,
                                                Wt2, bcat, qb, kb8, vb, sb);
    attn_kernel<<<NB4, 256, 0, stream>>>(qb, kb8, vb, sb, rs, csr, h2);
    bn_stats<128><<<256, 256, 0, stream>>>(h2, 128, bns + 128, bns + 256);
    bn_apply2<<<(NN*128+255)/256, 256, 0, stream>>>(h2, h1pre, nf,
                                                    bn1g, bn1b, bns + 0, bns + 64,
                                                    bn2g, bn2b, bns + 128, bns + 256,
                                                    x2r, x2b, x28);

    // ---- stage 3: SAGE ----
    sage_agg<<<NB4, 256, 0, stream>>>(x28, rs, csr, nmeanb);
    sage_gemm<<<NBG, 256, 0, stream>>>(x2b, nmeanb, Wsage, bl, h3);
    bn_stats<32><<<256, 256, 0, stream>>>(h3, 32, bns + 384, bns + 416);
    bn_apply3<<<(NN*32+255)/256, 256, 0, stream>>>(h3, x2r, bn3g, bn3b, bns + 384, bns + 416, out);
}